// Round 14
// baseline (345.934 us; speedup 1.0000x reference)
//
#include <hip/hip_runtime.h>
#include <hip/hip_bf16.h>
#include <stdint.h>

typedef __attribute__((ext_vector_type(8))) __bf16 bf16x8;
typedef __attribute__((ext_vector_type(4))) float f32x4;
typedef __attribute__((ext_vector_type(4))) int i32x4;
typedef unsigned short u16;

#define N_NODES 51200
#define N_EDGES 819200
#define F_IN 400
#define K1Q 448
#define H_DIM 256
#define C_OUT 2
#define N_GRAPHS 128
#define NODES_PER_GRAPH 400
#define NB_SCAN (N_NODES / 256)   // 200 blocks

__device__ __forceinline__ u16 f2bf(float f) {
  uint32_t u = __builtin_bit_cast(uint32_t, f);
  u = (u + 0x7fffu + ((u >> 16) & 1u)) >> 16;
  return (u16)u;
}

typedef const __attribute__((address_space(1))) unsigned int* gas_ptr;
typedef __attribute__((address_space(3))) unsigned int* las_ptr;
__device__ __forceinline__ void gl_lds16(const void* g, void* l) {
  __builtin_amdgcn_global_load_lds((gas_ptr)g, (las_ptr)l, 16, 0, 0);
}
__device__ __forceinline__ void wait_vm0()   { asm volatile("s_waitcnt vmcnt(0)" ::: "memory"); }
__device__ __forceinline__ void wait_vm5()   { asm volatile("s_waitcnt vmcnt(5)" ::: "memory"); }
__device__ __forceinline__ void wait_lgkm0() { asm volatile("s_waitcnt lgkmcnt(0)" ::: "memory"); }

// ------ multi-block zero (rocclr small-buffer fill path is serial) --------
__global__ void k_zero(int* __restrict__ p) {
  p[blockIdx.x * 256 + threadIdx.x] = 0;
}

// ------ merged histogram + rank handout: rank[e] = old count of dst[e] -----
__global__ void k_histrank(const int* __restrict__ dst, int* __restrict__ counts,
                           int* __restrict__ rank, int E) {
  int e = blockIdx.x * 256 + threadIdx.x;
  if (e < E) rank[e] = atomicAdd(&counts[dst[e]], 1);
}

// ---------------- hierarchical scan: phase 1, per-block sums --------------
__global__ __launch_bounds__(256) void k_reduce(const int* __restrict__ counts,
                                                int* __restrict__ bsum) {
  int i = blockIdx.x * 256 + threadIdx.x;
  int v = counts[i];
#pragma unroll
  for (int o = 32; o; o >>= 1) v += __shfl_xor(v, o);
  __shared__ int wsum[4];
  if ((threadIdx.x & 63) == 0) wsum[threadIdx.x >> 6] = v;
  __syncthreads();
  if (threadIdx.x == 0) bsum[blockIdx.x] = wsum[0] + wsum[1] + wsum[2] + wsum[3];
}

// ---------------- phase 2: scan the 200 block sums (one small block) ------
__global__ __launch_bounds__(256) void k_scantop(const int* __restrict__ bsum,
                                                 int* __restrict__ boff,
                                                 int* __restrict__ off_last) {
  __shared__ int s[256];
  int t = threadIdx.x;
  int v = (t < NB_SCAN) ? bsum[t] : 0;
  s[t] = v;
  __syncthreads();
  for (int d = 1; d < 256; d <<= 1) {
    int u = (t >= d) ? s[t - d] : 0;
    __syncthreads();
    s[t] += u;
    __syncthreads();
  }
  if (t < NB_SCAN) boff[t] = s[t] - v;   // exclusive prefix of block sums
  if (t == 0) *off_last = N_EDGES;       // off[N] = total edges
}

// ---------------- phase 3: local scan + block offset; also dis ------------
__global__ __launch_bounds__(256) void k_scanlocal(const int* __restrict__ counts,
                                                   const int* __restrict__ boff,
                                                   int* __restrict__ off,
                                                   float* __restrict__ dis) {
  __shared__ int s[256];
  int t = threadIdx.x;
  int i = blockIdx.x * 256 + t;
  int v = counts[i];
  s[t] = v;
  __syncthreads();
  for (int d = 1; d < 256; d <<= 1) {
    int u = (t >= d) ? s[t - d] : 0;
    __syncthreads();
    s[t] += u;
    __syncthreads();
  }
  int ex = boff[blockIdx.x] + s[t] - v;
  off[i] = ex;
  dis[i] = rsqrtf(1.0f + (float)v);
}

// --------- atomic-free placement: csr[off[d] + rank[e]] = src[e] ----------
__global__ void k_place(const int* __restrict__ src, const int* __restrict__ dst,
                        const int* __restrict__ rank, const int* __restrict__ off,
                        int* __restrict__ csr_src, int E) {
  int e = blockIdx.x * 256 + threadIdx.x;
  if (e < E) {
    int d = dst[e];
    csr_src[off[d] + rank[e]] = src[e];
  }
}

// ------- x -> per-row int8 (wave per row; lanes 0..49 hold 8 floats) ------
__global__ __launch_bounds__(256) void k_quantx(const float* __restrict__ x,
                                                int8_t* __restrict__ xq,
                                                float* __restrict__ sx) {
  int wid = threadIdx.x >> 6, lane = threadIdx.x & 63;
  int d = blockIdx.x * 4 + wid;
  float4 v0 = {0.f, 0.f, 0.f, 0.f}, v1 = {0.f, 0.f, 0.f, 0.f};
  if (lane < 50) {
    const float* p = x + (size_t)d * F_IN + lane * 8;
    v0 = *reinterpret_cast<const float4*>(p);
    v1 = *reinterpret_cast<const float4*>(p + 4);
  }
  float m = fmaxf(fmaxf(fmaxf(fabsf(v0.x), fabsf(v0.y)), fmaxf(fabsf(v0.z), fabsf(v0.w))),
                  fmaxf(fmaxf(fabsf(v1.x), fabsf(v1.y)), fmaxf(fabsf(v1.z), fabsf(v1.w))));
#pragma unroll
  for (int o = 32; o; o >>= 1) m = fmaxf(m, __shfl_xor(m, o));
  float inv = (m > 0.f) ? 127.0f / m : 0.f;
  if (lane < 56) {   // 56*8 = 448 bytes (zero pad past 400)
    uint32_t lo = 0, hi = 0;
    if (lane < 50) {
      int q0 = (int)rintf(v0.x * inv), q1 = (int)rintf(v0.y * inv);
      int q2 = (int)rintf(v0.z * inv), q3 = (int)rintf(v0.w * inv);
      int q4 = (int)rintf(v1.x * inv), q5 = (int)rintf(v1.y * inv);
      int q6 = (int)rintf(v1.z * inv), q7 = (int)rintf(v1.w * inv);
      lo = (uint32_t)(q0 & 255) | ((uint32_t)(q1 & 255) << 8) |
           ((uint32_t)(q2 & 255) << 16) | ((uint32_t)(q3 & 255) << 24);
      hi = (uint32_t)(q4 & 255) | ((uint32_t)(q5 & 255) << 8) |
           ((uint32_t)(q6 & 255) << 16) | ((uint32_t)(q7 & 255) << 24);
    }
    uint2 o8; o8.x = lo; o8.y = hi;
    *reinterpret_cast<uint2*>(xq + (size_t)d * K1Q + lane * 8) = o8;
  }
  if (lane == 0) sx[d] = m * (1.0f / 127.0f);
}

// ------- fused weight prep: blocks [0,64) -> W1 int8 + sw1; rest W2T bf16 -
__global__ __launch_bounds__(256) void k_prepw(const float* __restrict__ W1,
                                               const float* __restrict__ W2,
                                               int8_t* __restrict__ w1q,
                                               float* __restrict__ sw1,
                                               u16* __restrict__ W2T) {
  int b = blockIdx.x;
  if (b < H_DIM / 4) {
    int wid = threadIdx.x >> 6, lane = threadIdx.x & 63;
    int n = b * 4 + wid;
    float vals[7];
    float m = 0.f;
#pragma unroll
    for (int j = 0; j < 7; ++j) {
      int k = lane + j * 64;
      vals[j] = (k < F_IN) ? W1[(size_t)k * H_DIM + n] : 0.f;
      m = fmaxf(m, fabsf(vals[j]));
    }
#pragma unroll
    for (int o = 32; o; o >>= 1) m = fmaxf(m, __shfl_xor(m, o));
    float inv = (m > 0.f) ? 127.0f / m : 0.f;
#pragma unroll
    for (int j = 0; j < 7; ++j) {
      int k = lane + j * 64;
      w1q[(size_t)n * K1Q + k] = (int8_t)(int)rintf(vals[j] * inv);
    }
    if (lane == 0) sw1[n] = m * (1.0f / 127.0f);
  } else {
    int k = b - H_DIM / 4, n = threadIdx.x;
    W2T[n * H_DIM + k] = f2bf(W2[k * H_DIM + n]);
  }
}

// ------- layer-1 int8 MFMA GEMM: 2-deep counted-vmcnt pipe ----------------
// rs4 now SLICE-MAJOR: rs4[quad * N_NODES + row] (quad = wid = 64-col group)
template <int KB>
__global__ __launch_bounds__(256) void k_mm8(const int8_t* __restrict__ Aq,
                                             const float* __restrict__ srow,
                                             const int8_t* __restrict__ Bq,
                                             const float* __restrict__ scol,
                                             const float* __restrict__ dis,
                                             int8_t* __restrict__ Cq,
                                             float* __restrict__ rs4) {
  constexpr int NS = KB >> 6;
  __shared__ __align__(16) int8_t As[2][64 * 64];
  __shared__ __align__(16) int8_t Bs[2][256 * 64];
  const int tid = threadIdx.x;
  const int lane = tid & 63, wid = tid >> 6;
  const int lr = lane & 15, lg = lane >> 4;
  const int m0 = blockIdx.x * 64;
  const int aRow = tid >> 2;
  const int aSl = ((tid & 3) ^ ((tid >> 3) & 3)) << 4;
  const int bRow16 = lane >> 2;
  const int bSl = ((lane & 3) ^ ((lane >> 3) & 3)) << 4;
  const int rSl = (lg ^ ((lr >> 1) & 3)) << 4;

  auto stage = [&](int s, int b) {
    int k0 = s << 6;
    gl_lds16(Aq + (size_t)(m0 + aRow) * KB + k0 + aSl, (char*)As[b] + wid * 1024);
#pragma unroll
    for (int j = 0; j < 4; ++j) {
      int c = wid * 4 + j;
      gl_lds16(Bq + (size_t)(c * 16 + bRow16) * KB + k0 + bSl, (char*)Bs[b] + c * 1024);
    }
  };

  stage(0, 0);
  stage(1, 1);

  i32x4 acc[4][4] = {};
  for (int k = 0; k < NS; ++k) {
    const int b = k & 1;
    if (k + 1 < NS) wait_vm5(); else wait_vm0();
    __builtin_amdgcn_sched_barrier(0);
    __builtin_amdgcn_s_barrier();
    __builtin_amdgcn_sched_barrier(0);
    i32x4 af[4], bfr[4];
#pragma unroll
    for (int m = 0; m < 4; ++m)
      af[m] = *reinterpret_cast<const i32x4*>(&As[b][(m * 16 + lr) * 64 + rSl]);
#pragma unroll
    for (int n = 0; n < 4; ++n)
      bfr[n] = *reinterpret_cast<const i32x4*>(&Bs[b][(wid * 64 + n * 16 + lr) * 64 + rSl]);
    __builtin_amdgcn_sched_barrier(0);
    wait_lgkm0();
    __builtin_amdgcn_sched_barrier(0);
    __builtin_amdgcn_s_barrier();
    __builtin_amdgcn_sched_barrier(0);
    if (k + 2 < NS) stage(k + 2, b);
    __builtin_amdgcn_sched_barrier(0);
#pragma unroll
    for (int m = 0; m < 4; ++m)
#pragma unroll
      for (int n = 0; n < 4; ++n)
        acc[m][n] = __builtin_amdgcn_mfma_i32_16x16x64_i8(af[m], bfr[n], acc[m][n], 0, 0, 0);
  }

  float scv[4];
#pragma unroll
  for (int n = 0; n < 4; ++n) scv[n] = scol[wid * 64 + n * 16 + lr];
  float pam[4][4];
#pragma unroll
  for (int m = 0; m < 4; ++m)
#pragma unroll
    for (int r = 0; r < 4; ++r) {
      float v0 = fabsf((float)acc[m][0][r] * scv[0]);
      float v1 = fabsf((float)acc[m][1][r] * scv[1]);
      float v2 = fabsf((float)acc[m][2][r] * scv[2]);
      float v3 = fabsf((float)acc[m][3][r] * scv[3]);
      pam[m][r] = fmaxf(fmaxf(v0, v1), fmaxf(v2, v3));
    }
#pragma unroll
  for (int o = 1; o < 16; o <<= 1)
#pragma unroll
    for (int m = 0; m < 4; ++m)
#pragma unroll
      for (int r = 0; r < 4; ++r)
        pam[m][r] = fmaxf(pam[m][r], __shfl_xor(pam[m][r], o));
#pragma unroll
  for (int m = 0; m < 4; ++m)
#pragma unroll
    for (int r = 0; r < 4; ++r) {
      int grow = m0 + m * 16 + lg * 4 + r;
      float fm = fmaxf(pam[m][r], 1e-20f);
      float inv = 127.0f / fm;
      if (lr == 0)
        rs4[(size_t)wid * N_NODES + grow] = dis[grow] * srow[grow] * fm * (1.0f / 127.0f);
#pragma unroll
      for (int n = 0; n < 4; ++n) {
        int q = (int)rintf((float)acc[m][n][r] * scv[n] * inv);
        Cq[(size_t)grow * H_DIM + wid * 64 + n * 16 + lr] = (int8_t)q;
      }
    }
}

// ------- layer-2 bf16 MFMA GEMM (round-12 proven), slice-major rs4 --------
template <int KB>
__global__ __launch_bounds__(256) void k_mmB(const u16* __restrict__ A,
                                             const u16* __restrict__ BT,
                                             const float* __restrict__ dis,
                                             int8_t* __restrict__ Cq,
                                             float* __restrict__ rs4) {
  constexpr int NS = KB >> 5;
  __shared__ __align__(16) u16 As[2][64 * 32];
  __shared__ __align__(16) u16 Bs[2][256 * 32];
  const int tid = threadIdx.x;
  const int lane = tid & 63, wid = tid >> 6;
  const int lr = lane & 15, lg = lane >> 4;
  const int m0 = blockIdx.x * 64;
  const int sseg = (((lane & 3) ^ ((lane >> 3) & 3)) << 3);
  const int arow = tid >> 2;
  const int brow = lane >> 2;
  const int rs8 = ((lg ^ ((lr >> 1) & 3)) << 3);

  auto stage = [&](int s, int b) {
    int k0 = s << 5;
    gl_lds16(A + (size_t)(m0 + arow) * KB + k0 + sseg, (char*)As[b] + wid * 1024);
#pragma unroll
    for (int j = 0; j < 4; ++j) {
      int c = wid * 4 + j;
      gl_lds16(BT + (size_t)(c * 16 + brow) * KB + k0 + sseg, (char*)Bs[b] + c * 1024);
    }
  };

  stage(0, 0);
  stage(1, 1);

  f32x4 acc[4][4] = {};
  for (int k = 0; k < NS; ++k) {
    const int b = k & 1;
    if (k + 1 < NS) wait_vm5(); else wait_vm0();
    __builtin_amdgcn_sched_barrier(0);
    __builtin_amdgcn_s_barrier();
    __builtin_amdgcn_sched_barrier(0);
    bf16x8 af[4], bfr[4];
#pragma unroll
    for (int m = 0; m < 4; ++m)
      af[m] = *reinterpret_cast<const bf16x8*>(&As[b][(m * 16 + lr) * 32 + rs8]);
#pragma unroll
    for (int n = 0; n < 4; ++n)
      bfr[n] = *reinterpret_cast<const bf16x8*>(&Bs[b][(wid * 64 + n * 16 + lr) * 32 + rs8]);
    __builtin_amdgcn_sched_barrier(0);
    wait_lgkm0();
    __builtin_amdgcn_sched_barrier(0);
    __builtin_amdgcn_s_barrier();
    __builtin_amdgcn_sched_barrier(0);
    if (k + 2 < NS) stage(k + 2, b);
    __builtin_amdgcn_sched_barrier(0);
#pragma unroll
    for (int m = 0; m < 4; ++m)
#pragma unroll
      for (int n = 0; n < 4; ++n)
        acc[m][n] = __builtin_amdgcn_mfma_f32_16x16x32_bf16(af[m], bfr[n], acc[m][n], 0, 0, 0);
  }

  float pam[4][4];
#pragma unroll
  for (int m = 0; m < 4; ++m)
#pragma unroll
    for (int r = 0; r < 4; ++r) {
      float v0 = fabsf(acc[m][0][r]), v1 = fabsf(acc[m][1][r]);
      float v2 = fabsf(acc[m][2][r]), v3 = fabsf(acc[m][3][r]);
      pam[m][r] = fmaxf(fmaxf(v0, v1), fmaxf(v2, v3));
    }
#pragma unroll
  for (int o = 1; o < 16; o <<= 1)
#pragma unroll
    for (int m = 0; m < 4; ++m)
#pragma unroll
      for (int r = 0; r < 4; ++r)
        pam[m][r] = fmaxf(pam[m][r], __shfl_xor(pam[m][r], o));
#pragma unroll
  for (int m = 0; m < 4; ++m)
#pragma unroll
    for (int r = 0; r < 4; ++r) {
      int grow = m0 + m * 16 + lg * 4 + r;
      float fm = fmaxf(pam[m][r], 1e-20f);
      float inv = 127.0f / fm;
      if (lr == 0) rs4[(size_t)wid * N_NODES + grow] = dis[grow] * fm * (1.0f / 127.0f);
#pragma unroll
      for (int n = 0; n < 4; ++n) {
        int q = (int)rintf(acc[m][n][r] * inv);
        Cq[(size_t)grow * H_DIM + wid * 64 + n * 16 + lr] = (int8_t)q;
      }
    }
}

// ------- SLICED aggregation: block = one 64-feat slice x 4 nodes ----------
// Slice -> XCD-pair affinity via sl = (blockIdx%8)>>1 (consecutive blockIdx
// round-robin XCDs): each XCD's L2 only streams its 3.3MB slice of tq.
// Lane: g = lane>>4 (edge-in-group-of-4), c = lane&15 (dword = 4 feats).
// FUSE_T3=false: write bf16 slice of h. FUSE_T3=true: partial W3-dot -> t3p.
template <bool FUSE_T3>
__global__ __launch_bounds__(256) void k_aggs(const int8_t* __restrict__ tq,
                                              const float* __restrict__ rs4,
                                              const int* __restrict__ off,
                                              const int* __restrict__ csr,
                                              const float* __restrict__ dis,
                                              const float* __restrict__ bias,
                                              u16* __restrict__ h,
                                              const float* __restrict__ W3,
                                              float* __restrict__ t3p) {
  const int bid = blockIdx.x;
  const int wid = threadIdx.x >> 6, lane = threadIdx.x & 63;
  const int sl = (bid & 7) >> 1;                    // slice 0..3
  const int j = ((bid >> 3) << 1) | (bid & 1);      // 0..12799
  const int d = j * 4 + wid;
  const int g = lane >> 4;                          // edge slot 0..3
  const int c = lane & 15;                          // dword in 64B line
  const int colb = sl * 64 + c * 4;                 // byte offset in row
  const float* rs4s = rs4 + (size_t)sl * N_NODES;

  float a0 = 0.f, a1 = 0.f, a2 = 0.f, a3 = 0.f;
  if (g == 0) {   // self row once (groups summed later)
    uint32_t v = *reinterpret_cast<const uint32_t*>(tq + ((size_t)d << 8) + colb);
    float sc = rs4s[d];
    a0 = sc * (float)(int8_t)(v);
    a1 = sc * (float)(int8_t)(v >> 8);
    a2 = sc * (float)(int8_t)(v >> 16);
    a3 = sc * (float)(int8_t)(v >> 24);
  }
  int e = off[d], e1 = off[d + 1];
  while (e + 16 <= e1) {   // 16 edges: 4 per vmem instruction
    int i0 = csr[e + g], i1 = csr[e + 4 + g], i2 = csr[e + 8 + g], i3 = csr[e + 12 + g];
    uint32_t v0 = *reinterpret_cast<const uint32_t*>(tq + ((size_t)i0 << 8) + colb);
    uint32_t v1 = *reinterpret_cast<const uint32_t*>(tq + ((size_t)i1 << 8) + colb);
    uint32_t v2 = *reinterpret_cast<const uint32_t*>(tq + ((size_t)i2 << 8) + colb);
    uint32_t v3 = *reinterpret_cast<const uint32_t*>(tq + ((size_t)i3 << 8) + colb);
    float c0 = rs4s[i0], c1 = rs4s[i1], c2 = rs4s[i2], c3 = rs4s[i3];
    a0 += c0 * (float)(int8_t)(v0) + c1 * (float)(int8_t)(v1)
        + c2 * (float)(int8_t)(v2) + c3 * (float)(int8_t)(v3);
    a1 += c0 * (float)(int8_t)(v0 >> 8) + c1 * (float)(int8_t)(v1 >> 8)
        + c2 * (float)(int8_t)(v2 >> 8) + c3 * (float)(int8_t)(v3 >> 8);
    a2 += c0 * (float)(int8_t)(v0 >> 16) + c1 * (float)(int8_t)(v1 >> 16)
        + c2 * (float)(int8_t)(v2 >> 16) + c3 * (float)(int8_t)(v3 >> 16);
    a3 += c0 * (float)(int8_t)(v0 >> 24) + c1 * (float)(int8_t)(v1 >> 24)
        + c2 * (float)(int8_t)(v2 >> 24) + c3 * (float)(int8_t)(v3 >> 24);
    e += 16;
  }
  while (e < e1) {   // predicated 4-edge steps
    bool valid = (e + g) < e1;
    int idx = valid ? csr[e + g] : 0;
    float sc = valid ? rs4s[idx] : 0.f;
    uint32_t v = *reinterpret_cast<const uint32_t*>(tq + ((size_t)idx << 8) + colb);
    a0 += sc * (float)(int8_t)(v);
    a1 += sc * (float)(int8_t)(v >> 8);
    a2 += sc * (float)(int8_t)(v >> 16);
    a3 += sc * (float)(int8_t)(v >> 24);
    e += 4;
  }
  // combine the 4 edge groups
  a0 += __shfl_xor(a0, 16); a0 += __shfl_xor(a0, 32);
  a1 += __shfl_xor(a1, 16); a1 += __shfl_xor(a1, 32);
  a2 += __shfl_xor(a2, 16); a2 += __shfl_xor(a2, 32);
  a3 += __shfl_xor(a3, 16); a3 += __shfl_xor(a3, 32);

  float dd = dis[d];
  float4 bv = *reinterpret_cast<const float4*>(bias + colb);
  float r0 = fmaxf(dd * a0 + bv.x, 0.f);
  float r1 = fmaxf(dd * a1 + bv.y, 0.f);
  float r2 = fmaxf(dd * a2 + bv.z, 0.f);
  float r3 = fmaxf(dd * a3 + bv.w, 0.f);
  if (FUSE_T3) {
    float p0 = r0 * W3[(colb + 0) * 2]     + r1 * W3[(colb + 1) * 2]
             + r2 * W3[(colb + 2) * 2]     + r3 * W3[(colb + 3) * 2];
    float p1 = r0 * W3[(colb + 0) * 2 + 1] + r1 * W3[(colb + 1) * 2 + 1]
             + r2 * W3[(colb + 2) * 2 + 1] + r3 * W3[(colb + 3) * 2 + 1];
#pragma unroll
    for (int o = 1; o < 16; o <<= 1) { p0 += __shfl_xor(p0, o); p1 += __shfl_xor(p1, o); }
    if (lane == 0) {
      t3p[(size_t)d * 8 + sl * 2]     = dd * p0;
      t3p[(size_t)d * 8 + sl * 2 + 1] = dd * p1;
    }
  } else {
    if (g == 0) {
      ushort4 o;
      o.x = f2bf(r0); o.y = f2bf(r1); o.z = f2bf(r2); o.w = f2bf(r3);
      *reinterpret_cast<ushort4*>(h + ((size_t)d << 8) + colb) = o;
    }
  }
}

// ------- sum the 4 slice partials: t3[d] = sum_sl t3p[d][sl] --------------
__global__ __launch_bounds__(256) void k_sum4(const float* __restrict__ t3p,
                                              float* __restrict__ t3) {
  int d = blockIdx.x * 256 + threadIdx.x;
  f32x4 lo = *reinterpret_cast<const f32x4*>(t3p + (size_t)d * 8);
  f32x4 hi = *reinterpret_cast<const f32x4*>(t3p + (size_t)d * 8 + 4);
  t3[d * 2]     = lo[0] + lo[2] + hi[0] + hi[2];
  t3[d * 2 + 1] = lo[1] + lo[3] + hi[1] + hi[3];
}

// ------ fused layer-3 aggregation + mean pool: one block per graph --------
__global__ __launch_bounds__(448) void k_aggpool3(const float* __restrict__ t3,
                                                  const int* __restrict__ off,
                                                  const int* __restrict__ csr,
                                                  const float* __restrict__ dis,
                                                  const float* __restrict__ b3,
                                                  float* __restrict__ out) {
  int g = blockIdx.x, t = threadIdx.x;
  int lane = t & 63, wv = t >> 6;
  float a0 = 0.f, a1 = 0.f;
  if (t < NODES_PER_GRAPH) {
    int d = g * NODES_PER_GRAPH + t;
    a0 = t3[d * 2]; a1 = t3[d * 2 + 1];
    int e = off[d], e1 = off[d + 1];
    while (e + 4 <= e1) {
      int s0 = csr[e], s1 = csr[e + 1], s2 = csr[e + 2], s3 = csr[e + 3];
      float2 v0 = *reinterpret_cast<const float2*>(t3 + s0 * 2);
      float2 v1 = *reinterpret_cast<const float2*>(t3 + s1 * 2);
      float2 v2 = *reinterpret_cast<const float2*>(t3 + s2 * 2);
      float2 v3 = *reinterpret_cast<const float2*>(t3 + s3 * 2);
      a0 += v0.x + v1.x + v2.x + v3.x;
      a1 += v0.y + v1.y + v2.y + v3.y;
      e += 4;
    }
    while (e < e1) {
      float2 v = *reinterpret_cast<const float2*>(t3 + csr[e] * 2);
      a0 += v.x; a1 += v.y; ++e;
    }
    float dd = dis[d];
    a0 *= dd; a1 *= dd;
  }
#pragma unroll
  for (int o = 32; o; o >>= 1) { a0 += __shfl_xor(a0, o); a1 += __shfl_xor(a1, o); }
  __shared__ float w0[8], w1[8];
  if (lane == 0) { w0[wv] = a0; w1[wv] = a1; }
  __syncthreads();
  if (t == 0) {
    float s0 = 0.f, s1 = 0.f;
#pragma unroll
    for (int i = 0; i < 7; ++i) { s0 += w0[i]; s1 += w1[i]; }
    out[g * 2]     = s0 * (1.0f / NODES_PER_GRAPH) + b3[0];
    out[g * 2 + 1] = s1 * (1.0f / NODES_PER_GRAPH) + b3[1];
  }
}

extern "C" void kernel_launch(void* const* d_in, const int* in_sizes, int n_in,
                              void* d_out, int out_size, void* d_ws, size_t ws_size,
                              hipStream_t stream) {
  const float* x  = (const float*)d_in[0];
  const int*   ei = (const int*)d_in[1];
  const float* W1 = (const float*)d_in[2];
  const float* b1 = (const float*)d_in[3];
  const float* W2 = (const float*)d_in[4];
  const float* b2 = (const float*)d_in[5];
  const float* W3 = (const float*)d_in[6];
  const float* b3 = (const float*)d_in[7];
  float* out = (float*)d_out;
  const int E = N_EDGES;
  const int* src = ei;
  const int* dst = ei + E;

  char* ws = (char*)d_ws;
  size_t o = 0;
  auto alloc = [&](size_t bytes) -> void* {
    void* p = ws + o;
    o += (bytes + 255) & ~(size_t)255;
    return p;
  };
  int8_t* tQ   = (int8_t*)alloc((size_t)N_NODES * H_DIM);
  float* rs4   = (float*)alloc((size_t)N_NODES * 4 * 4);   // slice-major [4][N]
  u16* tB      = (u16*)alloc((size_t)N_NODES * H_DIM * 2);
  u16* W2T     = (u16*)alloc((size_t)H_DIM * H_DIM * 2);
  float* dis   = (float*)alloc((size_t)N_NODES * 4);
  int* counts  = (int*)alloc((size_t)N_NODES * 4);
  int* rank    = (int*)alloc((size_t)E * 4);
  int* csroff  = (int*)alloc((size_t)(N_NODES + 1) * 4);
  int* csr     = (int*)alloc((size_t)E * 4);
  float* t3    = (float*)alloc((size_t)N_NODES * 2 * 4);
  float* t3p   = (float*)alloc((size_t)N_NODES * 8 * 4);
  int* bsum    = (int*)alloc((size_t)NB_SCAN * 4);
  int* boff    = (int*)alloc((size_t)NB_SCAN * 4);
  int8_t* xq   = (int8_t*)alloc((size_t)N_NODES * K1Q);
  float* sx    = (float*)alloc((size_t)N_NODES * 4);
  int8_t* w1q  = (int8_t*)alloc((size_t)H_DIM * K1Q);
  float* sw1   = (float*)alloc((size_t)H_DIM * 4);

  k_zero<<<NB_SCAN, 256, 0, stream>>>(counts);
  k_histrank<<<(E + 255) / 256, 256, 0, stream>>>(dst, counts, rank, E);
  k_reduce<<<NB_SCAN, 256, 0, stream>>>(counts, bsum);
  k_scantop<<<1, 256, 0, stream>>>(bsum, boff, csroff + N_NODES);
  k_scanlocal<<<NB_SCAN, 256, 0, stream>>>(counts, boff, csroff, dis);
  k_place<<<(E + 255) / 256, 256, 0, stream>>>(src, dst, rank, csroff, csr, E);
  k_quantx<<<N_NODES / 4, 256, 0, stream>>>(x, xq, sx);
  k_prepw<<<H_DIM / 4 + H_DIM, 256, 0, stream>>>(W1, W2, w1q, sw1, W2T);

  // layer 1 (int8 MFMA, K=448)
  k_mm8<K1Q><<<N_NODES / 64, 256, 0, stream>>>(xq, sx, w1q, sw1, dis, tQ, rs4);
  k_aggs<false><<<N_NODES, 256, 0, stream>>>(tQ, rs4, csroff, csr, dis, b1,
                                             tB, nullptr, nullptr);
  // layer 2 (bf16 MFMA; agg fused with layer-3 matmul -> slice partials)
  k_mmB<H_DIM><<<N_NODES / 64, 256, 0, stream>>>(tB, W2T, dis, tQ, rs4);
  k_aggs<true><<<N_NODES, 256, 0, stream>>>(tQ, rs4, csroff, csr, dis, b2,
                                            nullptr, W3, t3p);
  k_sum4<<<NB_SCAN, 256, 0, stream>>>(t3p, t3);
  // layer 3 aggregation fused with mean pool
  k_aggpool3<<<N_GRAPHS, 448, 0, stream>>>(t3, csroff, csr, dis, b3, out);
}

// Round 15
// 223.242 us; speedup vs baseline: 1.5496x; 1.5496x over previous
//
#include <hip/hip_runtime.h>
#include <hip/hip_bf16.h>
#include <stdint.h>

typedef __attribute__((ext_vector_type(8))) __bf16 bf16x8;
typedef __attribute__((ext_vector_type(4))) float f32x4;
typedef __attribute__((ext_vector_type(4))) int i32x4;
typedef unsigned short u16;

#define N_NODES 51200
#define N_EDGES 819200
#define F_IN 400
#define K1Q 448
#define H_DIM 256
#define C_OUT 2
#define N_GRAPHS 128
#define NODES_PER_GRAPH 400
#define NB_SCAN (N_NODES / 256)   // 200 blocks

__device__ __forceinline__ u16 f2bf(float f) {
  uint32_t u = __builtin_bit_cast(uint32_t, f);
  u = (u + 0x7fffu + ((u >> 16) & 1u)) >> 16;
  return (u16)u;
}

typedef const __attribute__((address_space(1))) unsigned int* gas_ptr;
typedef __attribute__((address_space(3))) unsigned int* las_ptr;
__device__ __forceinline__ void gl_lds16(const void* g, void* l) {
  __builtin_amdgcn_global_load_lds((gas_ptr)g, (las_ptr)l, 16, 0, 0);
}
__device__ __forceinline__ void wait_vm0()   { asm volatile("s_waitcnt vmcnt(0)" ::: "memory"); }
__device__ __forceinline__ void wait_vm5()   { asm volatile("s_waitcnt vmcnt(5)" ::: "memory"); }
__device__ __forceinline__ void wait_lgkm0() { asm volatile("s_waitcnt lgkmcnt(0)" ::: "memory"); }

// ------ multi-block zero (rocclr small-buffer fill path is serial) --------
__global__ void k_zero(int* __restrict__ p) {
  p[blockIdx.x * 256 + threadIdx.x] = 0;
}

// ------ merged histogram + rank handout: rank[e] = old count of dst[e] -----
__global__ void k_histrank(const int* __restrict__ dst, int* __restrict__ counts,
                           int* __restrict__ rank, int E) {
  int e = blockIdx.x * 256 + threadIdx.x;
  if (e < E) rank[e] = atomicAdd(&counts[dst[e]], 1);
}

// ---------------- hierarchical scan: phase 1, per-block sums --------------
__global__ __launch_bounds__(256) void k_reduce(const int* __restrict__ counts,
                                                int* __restrict__ bsum) {
  int i = blockIdx.x * 256 + threadIdx.x;
  int v = counts[i];
#pragma unroll
  for (int o = 32; o; o >>= 1) v += __shfl_xor(v, o);
  __shared__ int wsum[4];
  if ((threadIdx.x & 63) == 0) wsum[threadIdx.x >> 6] = v;
  __syncthreads();
  if (threadIdx.x == 0) bsum[blockIdx.x] = wsum[0] + wsum[1] + wsum[2] + wsum[3];
}

// ---------------- phase 2: scan the 200 block sums (one small block) ------
__global__ __launch_bounds__(256) void k_scantop(const int* __restrict__ bsum,
                                                 int* __restrict__ boff,
                                                 int* __restrict__ off_last) {
  __shared__ int s[256];
  int t = threadIdx.x;
  int v = (t < NB_SCAN) ? bsum[t] : 0;
  s[t] = v;
  __syncthreads();
  for (int d = 1; d < 256; d <<= 1) {
    int u = (t >= d) ? s[t - d] : 0;
    __syncthreads();
    s[t] += u;
    __syncthreads();
  }
  if (t < NB_SCAN) boff[t] = s[t] - v;   // exclusive prefix of block sums
  if (t == 0) *off_last = N_EDGES;       // off[N] = total edges
}

// ---------------- phase 3: local scan + block offset; also dis ------------
__global__ __launch_bounds__(256) void k_scanlocal(const int* __restrict__ counts,
                                                   const int* __restrict__ boff,
                                                   int* __restrict__ off,
                                                   float* __restrict__ dis) {
  __shared__ int s[256];
  int t = threadIdx.x;
  int i = blockIdx.x * 256 + t;
  int v = counts[i];
  s[t] = v;
  __syncthreads();
  for (int d = 1; d < 256; d <<= 1) {
    int u = (t >= d) ? s[t - d] : 0;
    __syncthreads();
    s[t] += u;
    __syncthreads();
  }
  int ex = boff[blockIdx.x] + s[t] - v;
  off[i] = ex;
  dis[i] = rsqrtf(1.0f + (float)v);
}

// --------- atomic-free placement: csr[off[d] + rank[e]] = src[e] (u16) ----
__global__ void k_place(const int* __restrict__ src, const int* __restrict__ dst,
                        const int* __restrict__ rank, const int* __restrict__ off,
                        u16* __restrict__ csr_src, int E) {
  int e = blockIdx.x * 256 + threadIdx.x;
  if (e < E) {
    int d = dst[e];
    csr_src[off[d] + rank[e]] = (u16)src[e];
  }
}

// ------- x -> per-row int8 (wave per row; lanes 0..49 hold 8 floats) ------
__global__ __launch_bounds__(256) void k_quantx(const float* __restrict__ x,
                                                int8_t* __restrict__ xq,
                                                float* __restrict__ sx) {
  int wid = threadIdx.x >> 6, lane = threadIdx.x & 63;
  int d = blockIdx.x * 4 + wid;
  float4 v0 = {0.f, 0.f, 0.f, 0.f}, v1 = {0.f, 0.f, 0.f, 0.f};
  if (lane < 50) {
    const float* p = x + (size_t)d * F_IN + lane * 8;
    v0 = *reinterpret_cast<const float4*>(p);
    v1 = *reinterpret_cast<const float4*>(p + 4);
  }
  float m = fmaxf(fmaxf(fmaxf(fabsf(v0.x), fabsf(v0.y)), fmaxf(fabsf(v0.z), fabsf(v0.w))),
                  fmaxf(fmaxf(fabsf(v1.x), fabsf(v1.y)), fmaxf(fabsf(v1.z), fabsf(v1.w))));
#pragma unroll
  for (int o = 32; o; o >>= 1) m = fmaxf(m, __shfl_xor(m, o));
  float inv = (m > 0.f) ? 127.0f / m : 0.f;
  if (lane < 56) {   // 56*8 = 448 bytes (zero pad past 400)
    uint32_t lo = 0, hi = 0;
    if (lane < 50) {
      int q0 = (int)rintf(v0.x * inv), q1 = (int)rintf(v0.y * inv);
      int q2 = (int)rintf(v0.z * inv), q3 = (int)rintf(v0.w * inv);
      int q4 = (int)rintf(v1.x * inv), q5 = (int)rintf(v1.y * inv);
      int q6 = (int)rintf(v1.z * inv), q7 = (int)rintf(v1.w * inv);
      lo = (uint32_t)(q0 & 255) | ((uint32_t)(q1 & 255) << 8) |
           ((uint32_t)(q2 & 255) << 16) | ((uint32_t)(q3 & 255) << 24);
      hi = (uint32_t)(q4 & 255) | ((uint32_t)(q5 & 255) << 8) |
           ((uint32_t)(q6 & 255) << 16) | ((uint32_t)(q7 & 255) << 24);
    }
    uint2 o8; o8.x = lo; o8.y = hi;
    *reinterpret_cast<uint2*>(xq + (size_t)d * K1Q + lane * 8) = o8;
  }
  if (lane == 0) sx[d] = m * (1.0f / 127.0f);
}

// ------- fused weight prep: blocks [0,64) -> W1 int8 + sw1; rest W2T bf16 -
__global__ __launch_bounds__(256) void k_prepw(const float* __restrict__ W1,
                                               const float* __restrict__ W2,
                                               int8_t* __restrict__ w1q,
                                               float* __restrict__ sw1,
                                               u16* __restrict__ W2T) {
  int b = blockIdx.x;
  if (b < H_DIM / 4) {
    int wid = threadIdx.x >> 6, lane = threadIdx.x & 63;
    int n = b * 4 + wid;
    float vals[7];
    float m = 0.f;
#pragma unroll
    for (int j = 0; j < 7; ++j) {
      int k = lane + j * 64;
      vals[j] = (k < F_IN) ? W1[(size_t)k * H_DIM + n] : 0.f;
      m = fmaxf(m, fabsf(vals[j]));
    }
#pragma unroll
    for (int o = 32; o; o >>= 1) m = fmaxf(m, __shfl_xor(m, o));
    float inv = (m > 0.f) ? 127.0f / m : 0.f;
#pragma unroll
    for (int j = 0; j < 7; ++j) {
      int k = lane + j * 64;
      w1q[(size_t)n * K1Q + k] = (int8_t)(int)rintf(vals[j] * inv);
    }
    if (lane == 0) sw1[n] = m * (1.0f / 127.0f);
  } else {
    int k = b - H_DIM / 4, n = threadIdx.x;
    W2T[n * H_DIM + k] = f2bf(W2[k * H_DIM + n]);
  }
}

// ------- layer-1 int8 MFMA GEMM: 2-deep counted-vmcnt pipe ----------------
template <int KB>
__global__ __launch_bounds__(256) void k_mm8(const int8_t* __restrict__ Aq,
                                             const float* __restrict__ srow,
                                             const int8_t* __restrict__ Bq,
                                             const float* __restrict__ scol,
                                             const float* __restrict__ dis,
                                             int8_t* __restrict__ Cq,
                                             float* __restrict__ rs4) {
  constexpr int NS = KB >> 6;
  __shared__ __align__(16) int8_t As[2][64 * 64];
  __shared__ __align__(16) int8_t Bs[2][256 * 64];
  const int tid = threadIdx.x;
  const int lane = tid & 63, wid = tid >> 6;
  const int lr = lane & 15, lg = lane >> 4;
  const int m0 = blockIdx.x * 64;
  const int aRow = tid >> 2;
  const int aSl = ((tid & 3) ^ ((tid >> 3) & 3)) << 4;
  const int bRow16 = lane >> 2;
  const int bSl = ((lane & 3) ^ ((lane >> 3) & 3)) << 4;
  const int rSl = (lg ^ ((lr >> 1) & 3)) << 4;

  auto stage = [&](int s, int b) {
    int k0 = s << 6;
    gl_lds16(Aq + (size_t)(m0 + aRow) * KB + k0 + aSl, (char*)As[b] + wid * 1024);
#pragma unroll
    for (int j = 0; j < 4; ++j) {
      int c = wid * 4 + j;
      gl_lds16(Bq + (size_t)(c * 16 + bRow16) * KB + k0 + bSl, (char*)Bs[b] + c * 1024);
    }
  };

  stage(0, 0);
  stage(1, 1);

  i32x4 acc[4][4] = {};
  for (int k = 0; k < NS; ++k) {
    const int b = k & 1;
    if (k + 1 < NS) wait_vm5(); else wait_vm0();
    __builtin_amdgcn_sched_barrier(0);
    __builtin_amdgcn_s_barrier();
    __builtin_amdgcn_sched_barrier(0);
    i32x4 af[4], bfr[4];
#pragma unroll
    for (int m = 0; m < 4; ++m)
      af[m] = *reinterpret_cast<const i32x4*>(&As[b][(m * 16 + lr) * 64 + rSl]);
#pragma unroll
    for (int n = 0; n < 4; ++n)
      bfr[n] = *reinterpret_cast<const i32x4*>(&Bs[b][(wid * 64 + n * 16 + lr) * 64 + rSl]);
    __builtin_amdgcn_sched_barrier(0);
    wait_lgkm0();
    __builtin_amdgcn_sched_barrier(0);
    __builtin_amdgcn_s_barrier();
    __builtin_amdgcn_sched_barrier(0);
    if (k + 2 < NS) stage(k + 2, b);
    __builtin_amdgcn_sched_barrier(0);
#pragma unroll
    for (int m = 0; m < 4; ++m)
#pragma unroll
      for (int n = 0; n < 4; ++n)
        acc[m][n] = __builtin_amdgcn_mfma_i32_16x16x64_i8(af[m], bfr[n], acc[m][n], 0, 0, 0);
  }

  // ---- epilogue: dequant (scol; srow cancels in requant) + int8 requant
  float scv[4];
#pragma unroll
  for (int n = 0; n < 4; ++n) scv[n] = scol[wid * 64 + n * 16 + lr];
  float pam[4][4];
#pragma unroll
  for (int m = 0; m < 4; ++m)
#pragma unroll
    for (int r = 0; r < 4; ++r) {
      float v0 = fabsf((float)acc[m][0][r] * scv[0]);
      float v1 = fabsf((float)acc[m][1][r] * scv[1]);
      float v2 = fabsf((float)acc[m][2][r] * scv[2]);
      float v3 = fabsf((float)acc[m][3][r] * scv[3]);
      pam[m][r] = fmaxf(fmaxf(v0, v1), fmaxf(v2, v3));
    }
#pragma unroll
  for (int o = 1; o < 16; o <<= 1)
#pragma unroll
    for (int m = 0; m < 4; ++m)
#pragma unroll
      for (int r = 0; r < 4; ++r)
        pam[m][r] = fmaxf(pam[m][r], __shfl_xor(pam[m][r], o));
#pragma unroll
  for (int m = 0; m < 4; ++m)
#pragma unroll
    for (int r = 0; r < 4; ++r) {
      int grow = m0 + m * 16 + lg * 4 + r;
      float fm = fmaxf(pam[m][r], 1e-20f);
      float inv = 127.0f / fm;
      if (lr == 0) rs4[(size_t)grow * 4 + wid] = dis[grow] * srow[grow] * fm * (1.0f / 127.0f);
#pragma unroll
      for (int n = 0; n < 4; ++n) {
        int q = (int)rintf((float)acc[m][n][r] * scv[n] * inv);
        Cq[(size_t)grow * H_DIM + wid * 64 + n * 16 + lr] = (int8_t)q;
      }
    }
}

// ------- layer-2 bf16 MFMA GEMM: 2-deep counted-vmcnt pipe ----------------
template <int KB>
__global__ __launch_bounds__(256) void k_mmB(const u16* __restrict__ A,
                                             const u16* __restrict__ BT,
                                             const float* __restrict__ dis,
                                             int8_t* __restrict__ Cq,
                                             float* __restrict__ rs4) {
  constexpr int NS = KB >> 5;
  __shared__ __align__(16) u16 As[2][64 * 32];
  __shared__ __align__(16) u16 Bs[2][256 * 32];
  const int tid = threadIdx.x;
  const int lane = tid & 63, wid = tid >> 6;
  const int lr = lane & 15, lg = lane >> 4;
  const int m0 = blockIdx.x * 64;
  const int sseg = (((lane & 3) ^ ((lane >> 3) & 3)) << 3);
  const int arow = tid >> 2;
  const int brow = lane >> 2;
  const int rs8 = ((lg ^ ((lr >> 1) & 3)) << 3);

  auto stage = [&](int s, int b) {
    int k0 = s << 5;
    gl_lds16(A + (size_t)(m0 + arow) * KB + k0 + sseg, (char*)As[b] + wid * 1024);
#pragma unroll
    for (int j = 0; j < 4; ++j) {
      int c = wid * 4 + j;
      gl_lds16(BT + (size_t)(c * 16 + brow) * KB + k0 + sseg, (char*)Bs[b] + c * 1024);
    }
  };

  stage(0, 0);
  stage(1, 1);

  f32x4 acc[4][4] = {};
  for (int k = 0; k < NS; ++k) {
    const int b = k & 1;
    if (k + 1 < NS) wait_vm5(); else wait_vm0();
    __builtin_amdgcn_sched_barrier(0);
    __builtin_amdgcn_s_barrier();
    __builtin_amdgcn_sched_barrier(0);
    bf16x8 af[4], bfr[4];
#pragma unroll
    for (int m = 0; m < 4; ++m)
      af[m] = *reinterpret_cast<const bf16x8*>(&As[b][(m * 16 + lr) * 32 + rs8]);
#pragma unroll
    for (int n = 0; n < 4; ++n)
      bfr[n] = *reinterpret_cast<const bf16x8*>(&Bs[b][(wid * 64 + n * 16 + lr) * 32 + rs8]);
    __builtin_amdgcn_sched_barrier(0);
    wait_lgkm0();
    __builtin_amdgcn_sched_barrier(0);
    __builtin_amdgcn_s_barrier();
    __builtin_amdgcn_sched_barrier(0);
    if (k + 2 < NS) stage(k + 2, b);
    __builtin_amdgcn_sched_barrier(0);
#pragma unroll
    for (int m = 0; m < 4; ++m)
#pragma unroll
      for (int n = 0; n < 4; ++n)
        acc[m][n] = __builtin_amdgcn_mfma_f32_16x16x32_bf16(af[m], bfr[n], acc[m][n], 0, 0, 0);
  }

  // ---- epilogue: per-quadrant int8 quantization
  float pam[4][4];
#pragma unroll
  for (int m = 0; m < 4; ++m)
#pragma unroll
    for (int r = 0; r < 4; ++r) {
      float v0 = fabsf(acc[m][0][r]), v1 = fabsf(acc[m][1][r]);
      float v2 = fabsf(acc[m][2][r]), v3 = fabsf(acc[m][3][r]);
      pam[m][r] = fmaxf(fmaxf(v0, v1), fmaxf(v2, v3));
    }
#pragma unroll
  for (int o = 1; o < 16; o <<= 1)
#pragma unroll
    for (int m = 0; m < 4; ++m)
#pragma unroll
      for (int r = 0; r < 4; ++r)
        pam[m][r] = fmaxf(pam[m][r], __shfl_xor(pam[m][r], o));
#pragma unroll
  for (int m = 0; m < 4; ++m)
#pragma unroll
    for (int r = 0; r < 4; ++r) {
      int grow = m0 + m * 16 + lg * 4 + r;
      float fm = fmaxf(pam[m][r], 1e-20f);
      float inv = 127.0f / fm;
      if (lr == 0) rs4[(size_t)grow * 4 + wid] = dis[grow] * fm * (1.0f / 127.0f);
#pragma unroll
      for (int n = 0; n < 4; ++n) {
        int q = (int)rintf(acc[m][n][r] * inv);
        Cq[(size_t)grow * H_DIM + wid * 64 + n * 16 + lr] = (int8_t)q;
      }
    }
}

// ------- int8 gather group: U independent row loads + quadrant scales -----
template <int U>
__device__ __forceinline__ void gath8(const int8_t* __restrict__ tq,
                                      const float* __restrict__ rs4,
                                      const u16* __restrict__ csr, int e,
                                      int f0, int qo,
                                      float& a0, float& a1, float& a2, float& a3) {
  int s[U];
  uint32_t v[U];
  float sc[U];
#pragma unroll
  for (int i = 0; i < U; ++i) s[i] = csr[e + i];
#pragma unroll
  for (int i = 0; i < U; ++i) {
    v[i] = *reinterpret_cast<const uint32_t*>(tq + ((size_t)s[i] << 8) + f0);
    sc[i] = rs4[((size_t)s[i] << 2) + qo];
  }
#pragma unroll
  for (int i = 0; i < U; ++i) {
    a0 += sc[i] * (float)(int8_t)(v[i]);
    a1 += sc[i] * (float)(int8_t)(v[i] >> 8);
    a2 += sc[i] * (float)(int8_t)(v[i] >> 16);
    a3 += sc[i] * (float)(int8_t)(v[i] >> 24);
  }
}

// ------- aggregation on quantized pre-scaled rows ------------------------
template <bool FUSE_T3>
__global__ __launch_bounds__(256) void k_agg(const int8_t* __restrict__ tq,
                                             const float* __restrict__ rs4,
                                             const int* __restrict__ off,
                                             const u16* __restrict__ csr,
                                             const float* __restrict__ dis,
                                             const float* __restrict__ bias,
                                             u16* __restrict__ h,
                                             const float* __restrict__ W3,
                                             float* __restrict__ t3, int N) {
  int wid = threadIdx.x >> 6, lane = threadIdx.x & 63;
  int d = blockIdx.x * 4 + wid;
  if (d >= N) return;
  int f0 = lane * 4;
  int qo = lane >> 4;
  float a0, a1, a2, a3;
  {
    uint32_t v = *reinterpret_cast<const uint32_t*>(tq + ((size_t)d << 8) + f0);
    float sc = rs4[((size_t)d << 2) + qo];
    a0 = sc * (float)(int8_t)(v);
    a1 = sc * (float)(int8_t)(v >> 8);
    a2 = sc * (float)(int8_t)(v >> 16);
    a3 = sc * (float)(int8_t)(v >> 24);
  }
  int e = off[d], e1 = off[d + 1];
  while (e + 8 <= e1) { gath8<8>(tq, rs4, csr, e, f0, qo, a0, a1, a2, a3); e += 8; }
  if (e + 4 <= e1) { gath8<4>(tq, rs4, csr, e, f0, qo, a0, a1, a2, a3); e += 4; }
  if (e + 2 <= e1) { gath8<2>(tq, rs4, csr, e, f0, qo, a0, a1, a2, a3); e += 2; }
  if (e < e1)      { gath8<1>(tq, rs4, csr, e, f0, qo, a0, a1, a2, a3); }
  float dd = dis[d];
  float4 bv = *reinterpret_cast<const float4*>(bias + f0);
  float r0 = fmaxf(dd * a0 + bv.x, 0.f);
  float r1 = fmaxf(dd * a1 + bv.y, 0.f);
  float r2 = fmaxf(dd * a2 + bv.z, 0.f);
  float r3 = fmaxf(dd * a3 + bv.w, 0.f);
  if (FUSE_T3) {
    float p0 = r0 * W3[(f0 + 0) * 2]     + r1 * W3[(f0 + 1) * 2]
             + r2 * W3[(f0 + 2) * 2]     + r3 * W3[(f0 + 3) * 2];
    float p1 = r0 * W3[(f0 + 0) * 2 + 1] + r1 * W3[(f0 + 1) * 2 + 1]
             + r2 * W3[(f0 + 2) * 2 + 1] + r3 * W3[(f0 + 3) * 2 + 1];
#pragma unroll
    for (int o = 32; o; o >>= 1) { p0 += __shfl_xor(p0, o); p1 += __shfl_xor(p1, o); }
    if (lane == 0) {
      t3[d * 2] = dd * p0;
      t3[d * 2 + 1] = dd * p1;
    }
  } else {
    ushort4 o;
    o.x = f2bf(r0); o.y = f2bf(r1); o.z = f2bf(r2); o.w = f2bf(r3);
    *reinterpret_cast<ushort4*>(h + ((size_t)d << 8) + f0) = o;
  }
}

// ------ fused layer-3 aggregation + mean pool: one block per graph --------
__global__ __launch_bounds__(448) void k_aggpool3(const float* __restrict__ t3,
                                                  const int* __restrict__ off,
                                                  const u16* __restrict__ csr,
                                                  const float* __restrict__ dis,
                                                  const float* __restrict__ b3,
                                                  float* __restrict__ out) {
  int g = blockIdx.x, t = threadIdx.x;
  int lane = t & 63, wv = t >> 6;
  float a0 = 0.f, a1 = 0.f;
  if (t < NODES_PER_GRAPH) {
    int d = g * NODES_PER_GRAPH + t;
    a0 = t3[d * 2]; a1 = t3[d * 2 + 1];
    int e = off[d], e1 = off[d + 1];
    while (e + 4 <= e1) {
      int s0 = csr[e], s1 = csr[e + 1], s2 = csr[e + 2], s3 = csr[e + 3];
      float2 v0 = *reinterpret_cast<const float2*>(t3 + s0 * 2);
      float2 v1 = *reinterpret_cast<const float2*>(t3 + s1 * 2);
      float2 v2 = *reinterpret_cast<const float2*>(t3 + s2 * 2);
      float2 v3 = *reinterpret_cast<const float2*>(t3 + s3 * 2);
      a0 += v0.x + v1.x + v2.x + v3.x;
      a1 += v0.y + v1.y + v2.y + v3.y;
      e += 4;
    }
    while (e < e1) {
      float2 v = *reinterpret_cast<const float2*>(t3 + csr[e] * 2);
      a0 += v.x; a1 += v.y; ++e;
    }
    float dd = dis[d];
    a0 *= dd; a1 *= dd;
  }
#pragma unroll
  for (int o = 32; o; o >>= 1) { a0 += __shfl_xor(a0, o); a1 += __shfl_xor(a1, o); }
  __shared__ float w0[8], w1[8];
  if (lane == 0) { w0[wv] = a0; w1[wv] = a1; }
  __syncthreads();
  if (t == 0) {
    float s0 = 0.f, s1 = 0.f;
#pragma unroll
    for (int i = 0; i < 7; ++i) { s0 += w0[i]; s1 += w1[i]; }
    out[g * 2]     = s0 * (1.0f / NODES_PER_GRAPH) + b3[0];
    out[g * 2 + 1] = s1 * (1.0f / NODES_PER_GRAPH) + b3[1];
  }
}

extern "C" void kernel_launch(void* const* d_in, const int* in_sizes, int n_in,
                              void* d_out, int out_size, void* d_ws, size_t ws_size,
                              hipStream_t stream) {
  const float* x  = (const float*)d_in[0];
  const int*   ei = (const int*)d_in[1];
  const float* W1 = (const float*)d_in[2];
  const float* b1 = (const float*)d_in[3];
  const float* W2 = (const float*)d_in[4];
  const float* b2 = (const float*)d_in[5];
  const float* W3 = (const float*)d_in[6];
  const float* b3 = (const float*)d_in[7];
  float* out = (float*)d_out;
  const int E = N_EDGES;
  const int* src = ei;
  const int* dst = ei + E;

  char* ws = (char*)d_ws;
  size_t o = 0;
  auto alloc = [&](size_t bytes) -> void* {
    void* p = ws + o;
    o += (bytes + 255) & ~(size_t)255;
    return p;
  };
  int8_t* tQ   = (int8_t*)alloc((size_t)N_NODES * H_DIM);
  float* rs4   = (float*)alloc((size_t)N_NODES * 4 * 4);
  u16* tB      = (u16*)alloc((size_t)N_NODES * H_DIM * 2);
  u16* W2T     = (u16*)alloc((size_t)H_DIM * H_DIM * 2);
  float* dis   = (float*)alloc((size_t)N_NODES * 4);
  int* counts  = (int*)alloc((size_t)N_NODES * 4);
  int* rank    = (int*)alloc((size_t)E * 4);
  int* csroff  = (int*)alloc((size_t)(N_NODES + 1) * 4);
  u16* csr     = (u16*)alloc((size_t)E * 2);
  float* t3    = (float*)alloc((size_t)N_NODES * 2 * 4);
  int* bsum    = (int*)alloc((size_t)NB_SCAN * 4);
  int* boff    = (int*)alloc((size_t)NB_SCAN * 4);
  int8_t* xq   = (int8_t*)alloc((size_t)N_NODES * K1Q);
  float* sx    = (float*)alloc((size_t)N_NODES * 4);
  int8_t* w1q  = (int8_t*)alloc((size_t)H_DIM * K1Q);
  float* sw1   = (float*)alloc((size_t)H_DIM * 4);

  k_zero<<<NB_SCAN, 256, 0, stream>>>(counts);
  k_histrank<<<(E + 255) / 256, 256, 0, stream>>>(dst, counts, rank, E);
  k_reduce<<<NB_SCAN, 256, 0, stream>>>(counts, bsum);
  k_scantop<<<1, 256, 0, stream>>>(bsum, boff, csroff + N_NODES);
  k_scanlocal<<<NB_SCAN, 256, 0, stream>>>(counts, boff, csroff, dis);
  k_place<<<(E + 255) / 256, 256, 0, stream>>>(src, dst, rank, csroff, csr, E);
  k_quantx<<<N_NODES / 4, 256, 0, stream>>>(x, xq, sx);
  k_prepw<<<H_DIM / 4 + H_DIM, 256, 0, stream>>>(W1, W2, w1q, sw1, W2T);

  // layer 1 (int8 MFMA, K=448)
  k_mm8<K1Q><<<N_NODES / 64, 256, 0, stream>>>(xq, sx, w1q, sw1, dis, tQ, rs4);
  k_agg<false><<<N_NODES / 4, 256, 0, stream>>>(tQ, rs4, csroff, csr, dis, b1,
                                                tB, nullptr, nullptr, N_NODES);
  // layer 2 (bf16 MFMA; agg fused with layer-3 matmul -> t3)
  k_mmB<H_DIM><<<N_NODES / 64, 256, 0, stream>>>(tB, W2T, dis, tQ, rs4);
  k_agg<true><<<N_NODES / 4, 256, 0, stream>>>(tQ, rs4, csroff, csr, dis, b2,
                                               nullptr, W3, t3, N_NODES);
  // layer 3 aggregation fused with mean pool
  k_aggpool3<<<N_GRAPHS, 448, 0, stream>>>(t3, csroff, csr, dis, b3, out);
}

// Round 16
// 209.613 us; speedup vs baseline: 1.6503x; 1.0650x over previous
//
#include <hip/hip_runtime.h>
#include <hip/hip_bf16.h>
#include <stdint.h>

typedef __attribute__((ext_vector_type(8))) __bf16 bf16x8;
typedef __attribute__((ext_vector_type(4))) float f32x4;
typedef __attribute__((ext_vector_type(4))) int i32x4;
typedef unsigned short u16;

#define N_NODES 51200
#define N_EDGES 819200
#define F_IN 400
#define K1Q 448
#define H_DIM 256
#define C_OUT 2
#define N_GRAPHS 128
#define NODES_PER_GRAPH 400
#define NB_SCAN (N_NODES / 256)   // 200 blocks
#define HB 3200                   // histrank blocks in fuse1
#define QB 12800                  // quantx blocks in fuse1
#define MB 800                    // mm8 blocks in fuse2

__device__ __forceinline__ u16 f2bf(float f) {
  uint32_t u = __builtin_bit_cast(uint32_t, f);
  u = (u + 0x7fffu + ((u >> 16) & 1u)) >> 16;
  return (u16)u;
}

typedef const __attribute__((address_space(1))) unsigned int* gas_ptr;
typedef __attribute__((address_space(3))) unsigned int* las_ptr;
__device__ __forceinline__ void gl_lds16(const void* g, void* l) {
  __builtin_amdgcn_global_load_lds((gas_ptr)g, (las_ptr)l, 16, 0, 0);
}
__device__ __forceinline__ void wait_vm0()   { asm volatile("s_waitcnt vmcnt(0)" ::: "memory"); }
__device__ __forceinline__ void wait_vm5()   { asm volatile("s_waitcnt vmcnt(5)" ::: "memory"); }
__device__ __forceinline__ void wait_lgkm0() { asm volatile("s_waitcnt lgkmcnt(0)" ::: "memory"); }

// ------ multi-block zero (rocclr small-buffer fill path is serial) --------
__global__ void k_zero(int* __restrict__ p) {
  p[blockIdx.x * 256 + threadIdx.x] = 0;
}

// ===== FUSE 1: histrank [0,HB) | quantx [HB,HB+QB) | prepw [HB+QB,..) =====
__global__ __launch_bounds__(256) void k_fuse1(
    const int* __restrict__ dst, int* __restrict__ counts, int* __restrict__ rank,
    const float* __restrict__ x, int8_t* __restrict__ xq, float* __restrict__ sx,
    const float* __restrict__ W1, const float* __restrict__ W2,
    int8_t* __restrict__ w1q, float* __restrict__ sw1, u16* __restrict__ W2T) {
  int bid = blockIdx.x;
  int wid = threadIdx.x >> 6, lane = threadIdx.x & 63;
  if (bid < HB) {
    // ---- histogram + rank handout
    int e = bid * 256 + threadIdx.x;
    rank[e] = atomicAdd(&counts[dst[e]], 1);
  } else if (bid < HB + QB) {
    // ---- x -> per-row int8
    int d = (bid - HB) * 4 + wid;
    float4 v0 = {0.f, 0.f, 0.f, 0.f}, v1 = {0.f, 0.f, 0.f, 0.f};
    if (lane < 50) {
      const float* p = x + (size_t)d * F_IN + lane * 8;
      v0 = *reinterpret_cast<const float4*>(p);
      v1 = *reinterpret_cast<const float4*>(p + 4);
    }
    float m = fmaxf(fmaxf(fmaxf(fabsf(v0.x), fabsf(v0.y)), fmaxf(fabsf(v0.z), fabsf(v0.w))),
                    fmaxf(fmaxf(fabsf(v1.x), fabsf(v1.y)), fmaxf(fabsf(v1.z), fabsf(v1.w))));
#pragma unroll
    for (int o = 32; o; o >>= 1) m = fmaxf(m, __shfl_xor(m, o));
    float inv = (m > 0.f) ? 127.0f / m : 0.f;
    if (lane < 56) {
      uint32_t lo = 0, hi = 0;
      if (lane < 50) {
        int q0 = (int)rintf(v0.x * inv), q1 = (int)rintf(v0.y * inv);
        int q2 = (int)rintf(v0.z * inv), q3 = (int)rintf(v0.w * inv);
        int q4 = (int)rintf(v1.x * inv), q5 = (int)rintf(v1.y * inv);
        int q6 = (int)rintf(v1.z * inv), q7 = (int)rintf(v1.w * inv);
        lo = (uint32_t)(q0 & 255) | ((uint32_t)(q1 & 255) << 8) |
             ((uint32_t)(q2 & 255) << 16) | ((uint32_t)(q3 & 255) << 24);
        hi = (uint32_t)(q4 & 255) | ((uint32_t)(q5 & 255) << 8) |
             ((uint32_t)(q6 & 255) << 16) | ((uint32_t)(q7 & 255) << 24);
      }
      uint2 o8; o8.x = lo; o8.y = hi;
      *reinterpret_cast<uint2*>(xq + (size_t)d * K1Q + lane * 8) = o8;
    }
    if (lane == 0) sx[d] = m * (1.0f / 127.0f);
  } else {
    // ---- weight prep
    int b = bid - HB - QB;
    if (b < H_DIM / 4) {
      int n = b * 4 + wid;
      float vals[7];
      float m = 0.f;
#pragma unroll
      for (int j = 0; j < 7; ++j) {
        int k = lane + j * 64;
        vals[j] = (k < F_IN) ? W1[(size_t)k * H_DIM + n] : 0.f;
        m = fmaxf(m, fabsf(vals[j]));
      }
#pragma unroll
      for (int o = 32; o; o >>= 1) m = fmaxf(m, __shfl_xor(m, o));
      float inv = (m > 0.f) ? 127.0f / m : 0.f;
#pragma unroll
      for (int j = 0; j < 7; ++j) {
        int k = lane + j * 64;
        w1q[(size_t)n * K1Q + k] = (int8_t)(int)rintf(vals[j] * inv);
      }
      if (lane == 0) sw1[n] = m * (1.0f / 127.0f);
    } else {
      int k = b - H_DIM / 4, n = threadIdx.x;
      W2T[n * H_DIM + k] = f2bf(W2[k * H_DIM + n]);
    }
  }
}

// ---------------- hierarchical scan: phase 1, per-block sums --------------
__global__ __launch_bounds__(256) void k_reduce(const int* __restrict__ counts,
                                                int* __restrict__ bsum) {
  int i = blockIdx.x * 256 + threadIdx.x;
  int v = counts[i];
#pragma unroll
  for (int o = 32; o; o >>= 1) v += __shfl_xor(v, o);
  __shared__ int wsum[4];
  if ((threadIdx.x & 63) == 0) wsum[threadIdx.x >> 6] = v;
  __syncthreads();
  if (threadIdx.x == 0) bsum[blockIdx.x] = wsum[0] + wsum[1] + wsum[2] + wsum[3];
}

// ---------------- phase 2: scan the 200 block sums (one small block) ------
__global__ __launch_bounds__(256) void k_scantop(const int* __restrict__ bsum,
                                                 int* __restrict__ boff,
                                                 int* __restrict__ off_last) {
  __shared__ int s[256];
  int t = threadIdx.x;
  int v = (t < NB_SCAN) ? bsum[t] : 0;
  s[t] = v;
  __syncthreads();
  for (int d = 1; d < 256; d <<= 1) {
    int u = (t >= d) ? s[t - d] : 0;
    __syncthreads();
    s[t] += u;
    __syncthreads();
  }
  if (t < NB_SCAN) boff[t] = s[t] - v;   // exclusive prefix of block sums
  if (t == 0) *off_last = N_EDGES;       // off[N] = total edges
}

// ---------------- phase 3: local scan + block offset; also dis ------------
__global__ __launch_bounds__(256) void k_scanlocal(const int* __restrict__ counts,
                                                   const int* __restrict__ boff,
                                                   int* __restrict__ off,
                                                   float* __restrict__ dis) {
  __shared__ int s[256];
  int t = threadIdx.x;
  int i = blockIdx.x * 256 + t;
  int v = counts[i];
  s[t] = v;
  __syncthreads();
  for (int d = 1; d < 256; d <<= 1) {
    int u = (t >= d) ? s[t - d] : 0;
    __syncthreads();
    s[t] += u;
    __syncthreads();
  }
  int ex = boff[blockIdx.x] + s[t] - v;
  off[i] = ex;
  dis[i] = rsqrtf(1.0f + (float)v);
}

// ===== FUSE 2: mm8 (layer-1 int8 GEMM) [0,MB) | place [MB,MB+3200) ========
__global__ __launch_bounds__(256) void k_fuse2(
    const int8_t* __restrict__ Aq, const float* __restrict__ srow,
    const int8_t* __restrict__ Bq, const float* __restrict__ scol,
    const float* __restrict__ dis, int8_t* __restrict__ Cq, float* __restrict__ rs4,
    const int* __restrict__ src, const int* __restrict__ dst,
    const int* __restrict__ rank, const int* __restrict__ off,
    u16* __restrict__ csr_src) {
  constexpr int KB = K1Q, NS = KB >> 6;   // 7
  __shared__ __align__(16) int8_t As[2][64 * 64];
  __shared__ __align__(16) int8_t Bs[2][256 * 64];
  const int bid = blockIdx.x;
  if (bid >= MB) {
    // ---- atomic-free placement (u16)
    int e = (bid - MB) * 256 + threadIdx.x;
    int d = dst[e];
    csr_src[off[d] + rank[e]] = (u16)src[e];
    return;
  }
  const int tid = threadIdx.x;
  const int lane = tid & 63, wid = tid >> 6;
  const int lr = lane & 15, lg = lane >> 4;
  const int m0 = bid * 64;
  const int aRow = tid >> 2;
  const int aSl = ((tid & 3) ^ ((tid >> 3) & 3)) << 4;
  const int bRow16 = lane >> 2;
  const int bSl = ((lane & 3) ^ ((lane >> 3) & 3)) << 4;
  const int rSl = (lg ^ ((lr >> 1) & 3)) << 4;

  auto stage = [&](int s, int b) {
    int k0 = s << 6;
    gl_lds16(Aq + (size_t)(m0 + aRow) * KB + k0 + aSl, (char*)As[b] + wid * 1024);
#pragma unroll
    for (int j = 0; j < 4; ++j) {
      int c = wid * 4 + j;
      gl_lds16(Bq + (size_t)(c * 16 + bRow16) * KB + k0 + bSl, (char*)Bs[b] + c * 1024);
    }
  };

  stage(0, 0);
  stage(1, 1);

  i32x4 acc[4][4] = {};
  for (int k = 0; k < NS; ++k) {
    const int b = k & 1;
    if (k + 1 < NS) wait_vm5(); else wait_vm0();
    __builtin_amdgcn_sched_barrier(0);
    __builtin_amdgcn_s_barrier();
    __builtin_amdgcn_sched_barrier(0);
    i32x4 af[4], bfr[4];
#pragma unroll
    for (int m = 0; m < 4; ++m)
      af[m] = *reinterpret_cast<const i32x4*>(&As[b][(m * 16 + lr) * 64 + rSl]);
#pragma unroll
    for (int n = 0; n < 4; ++n)
      bfr[n] = *reinterpret_cast<const i32x4*>(&Bs[b][(wid * 64 + n * 16 + lr) * 64 + rSl]);
    __builtin_amdgcn_sched_barrier(0);
    wait_lgkm0();
    __builtin_amdgcn_sched_barrier(0);
    __builtin_amdgcn_s_barrier();
    __builtin_amdgcn_sched_barrier(0);
    if (k + 2 < NS) stage(k + 2, b);
    __builtin_amdgcn_sched_barrier(0);
#pragma unroll
    for (int m = 0; m < 4; ++m)
#pragma unroll
      for (int n = 0; n < 4; ++n)
        acc[m][n] = __builtin_amdgcn_mfma_i32_16x16x64_i8(af[m], bfr[n], acc[m][n], 0, 0, 0);
  }

  // ---- epilogue: dequant (scol; srow cancels in requant) + int8 requant
  float scv[4];
#pragma unroll
  for (int n = 0; n < 4; ++n) scv[n] = scol[wid * 64 + n * 16 + lr];
  float pam[4][4];
#pragma unroll
  for (int m = 0; m < 4; ++m)
#pragma unroll
    for (int r = 0; r < 4; ++r) {
      float v0 = fabsf((float)acc[m][0][r] * scv[0]);
      float v1 = fabsf((float)acc[m][1][r] * scv[1]);
      float v2 = fabsf((float)acc[m][2][r] * scv[2]);
      float v3 = fabsf((float)acc[m][3][r] * scv[3]);
      pam[m][r] = fmaxf(fmaxf(v0, v1), fmaxf(v2, v3));
    }
#pragma unroll
  for (int o = 1; o < 16; o <<= 1)
#pragma unroll
    for (int m = 0; m < 4; ++m)
#pragma unroll
      for (int r = 0; r < 4; ++r)
        pam[m][r] = fmaxf(pam[m][r], __shfl_xor(pam[m][r], o));
#pragma unroll
  for (int m = 0; m < 4; ++m)
#pragma unroll
    for (int r = 0; r < 4; ++r) {
      int grow = m0 + m * 16 + lg * 4 + r;
      float fm = fmaxf(pam[m][r], 1e-20f);
      float inv = 127.0f / fm;
      if (lr == 0) rs4[(size_t)grow * 4 + wid] = dis[grow] * srow[grow] * fm * (1.0f / 127.0f);
#pragma unroll
      for (int n = 0; n < 4; ++n) {
        int q = (int)rintf((float)acc[m][n][r] * scv[n] * inv);
        Cq[(size_t)grow * H_DIM + wid * 64 + n * 16 + lr] = (int8_t)q;
      }
    }
}

// ------- layer-2 bf16 MFMA GEMM: 2-deep counted-vmcnt pipe ----------------
template <int KB>
__global__ __launch_bounds__(256) void k_mmB(const u16* __restrict__ A,
                                             const u16* __restrict__ BT,
                                             const float* __restrict__ dis,
                                             int8_t* __restrict__ Cq,
                                             float* __restrict__ rs4) {
  constexpr int NS = KB >> 5;
  __shared__ __align__(16) u16 As[2][64 * 32];
  __shared__ __align__(16) u16 Bs[2][256 * 32];
  const int tid = threadIdx.x;
  const int lane = tid & 63, wid = tid >> 6;
  const int lr = lane & 15, lg = lane >> 4;
  const int m0 = blockIdx.x * 64;
  const int sseg = (((lane & 3) ^ ((lane >> 3) & 3)) << 3);
  const int arow = tid >> 2;
  const int brow = lane >> 2;
  const int rs8 = ((lg ^ ((lr >> 1) & 3)) << 3);

  auto stage = [&](int s, int b) {
    int k0 = s << 5;
    gl_lds16(A + (size_t)(m0 + arow) * KB + k0 + sseg, (char*)As[b] + wid * 1024);
#pragma unroll
    for (int j = 0; j < 4; ++j) {
      int c = wid * 4 + j;
      gl_lds16(BT + (size_t)(c * 16 + brow) * KB + k0 + sseg, (char*)Bs[b] + c * 1024);
    }
  };

  stage(0, 0);
  stage(1, 1);

  f32x4 acc[4][4] = {};
  for (int k = 0; k < NS; ++k) {
    const int b = k & 1;
    if (k + 1 < NS) wait_vm5(); else wait_vm0();
    __builtin_amdgcn_sched_barrier(0);
    __builtin_amdgcn_s_barrier();
    __builtin_amdgcn_sched_barrier(0);
    bf16x8 af[4], bfr[4];
#pragma unroll
    for (int m = 0; m < 4; ++m)
      af[m] = *reinterpret_cast<const bf16x8*>(&As[b][(m * 16 + lr) * 32 + rs8]);
#pragma unroll
    for (int n = 0; n < 4; ++n)
      bfr[n] = *reinterpret_cast<const bf16x8*>(&Bs[b][(wid * 64 + n * 16 + lr) * 32 + rs8]);
    __builtin_amdgcn_sched_barrier(0);
    wait_lgkm0();
    __builtin_amdgcn_sched_barrier(0);
    __builtin_amdgcn_s_barrier();
    __builtin_amdgcn_sched_barrier(0);
    if (k + 2 < NS) stage(k + 2, b);
    __builtin_amdgcn_sched_barrier(0);
#pragma unroll
    for (int m = 0; m < 4; ++m)
#pragma unroll
      for (int n = 0; n < 4; ++n)
        acc[m][n] = __builtin_amdgcn_mfma_f32_16x16x32_bf16(af[m], bfr[n], acc[m][n], 0, 0, 0);
  }

  // ---- epilogue: per-quadrant int8 quantization
  float pam[4][4];
#pragma unroll
  for (int m = 0; m < 4; ++m)
#pragma unroll
    for (int r = 0; r < 4; ++r) {
      float v0 = fabsf(acc[m][0][r]), v1 = fabsf(acc[m][1][r]);
      float v2 = fabsf(acc[m][2][r]), v3 = fabsf(acc[m][3][r]);
      pam[m][r] = fmaxf(fmaxf(v0, v1), fmaxf(v2, v3));
    }
#pragma unroll
  for (int o = 1; o < 16; o <<= 1)
#pragma unroll
    for (int m = 0; m < 4; ++m)
#pragma unroll
      for (int r = 0; r < 4; ++r)
        pam[m][r] = fmaxf(pam[m][r], __shfl_xor(pam[m][r], o));
#pragma unroll
  for (int m = 0; m < 4; ++m)
#pragma unroll
    for (int r = 0; r < 4; ++r) {
      int grow = m0 + m * 16 + lg * 4 + r;
      float fm = fmaxf(pam[m][r], 1e-20f);
      float inv = 127.0f / fm;
      if (lr == 0) rs4[(size_t)grow * 4 + wid] = dis[grow] * fm * (1.0f / 127.0f);
#pragma unroll
      for (int n = 0; n < 4; ++n) {
        int q = (int)rintf(acc[m][n][r] * inv);
        Cq[(size_t)grow * H_DIM + wid * 64 + n * 16 + lr] = (int8_t)q;
      }
    }
}

// ------- int8 gather group: U independent row loads + quadrant scales -----
template <int U>
__device__ __forceinline__ void gath8(const int8_t* __restrict__ tq,
                                      const float* __restrict__ rs4,
                                      const u16* __restrict__ csr, int e,
                                      int f0, int qo,
                                      float& a0, float& a1, float& a2, float& a3) {
  int s[U];
  uint32_t v[U];
  float sc[U];
#pragma unroll
  for (int i = 0; i < U; ++i) s[i] = csr[e + i];
#pragma unroll
  for (int i = 0; i < U; ++i) {
    v[i] = *reinterpret_cast<const uint32_t*>(tq + ((size_t)s[i] << 8) + f0);
    sc[i] = rs4[((size_t)s[i] << 2) + qo];
  }
#pragma unroll
  for (int i = 0; i < U; ++i) {
    a0 += sc[i] * (float)(int8_t)(v[i]);
    a1 += sc[i] * (float)(int8_t)(v[i] >> 8);
    a2 += sc[i] * (float)(int8_t)(v[i] >> 16);
    a3 += sc[i] * (float)(int8_t)(v[i] >> 24);
  }
}

// ------- aggregation on quantized pre-scaled rows ------------------------
template <bool FUSE_T3>
__global__ __launch_bounds__(256) void k_agg(const int8_t* __restrict__ tq,
                                             const float* __restrict__ rs4,
                                             const int* __restrict__ off,
                                             const u16* __restrict__ csr,
                                             const float* __restrict__ dis,
                                             const float* __restrict__ bias,
                                             u16* __restrict__ h,
                                             const float* __restrict__ W3,
                                             float* __restrict__ t3, int N) {
  int wid = threadIdx.x >> 6, lane = threadIdx.x & 63;
  int d = blockIdx.x * 4 + wid;
  if (d >= N) return;
  int f0 = lane * 4;
  int qo = lane >> 4;
  float a0, a1, a2, a3;
  {
    uint32_t v = *reinterpret_cast<const uint32_t*>(tq + ((size_t)d << 8) + f0);
    float sc = rs4[((size_t)d << 2) + qo];
    a0 = sc * (float)(int8_t)(v);
    a1 = sc * (float)(int8_t)(v >> 8);
    a2 = sc * (float)(int8_t)(v >> 16);
    a3 = sc * (float)(int8_t)(v >> 24);
  }
  int e = off[d], e1 = off[d + 1];
  while (e + 8 <= e1) { gath8<8>(tq, rs4, csr, e, f0, qo, a0, a1, a2, a3); e += 8; }
  if (e + 4 <= e1) { gath8<4>(tq, rs4, csr, e, f0, qo, a0, a1, a2, a3); e += 4; }
  if (e + 2 <= e1) { gath8<2>(tq, rs4, csr, e, f0, qo, a0, a1, a2, a3); e += 2; }
  if (e < e1)      { gath8<1>(tq, rs4, csr, e, f0, qo, a0, a1, a2, a3); }
  float dd = dis[d];
  float4 bv = *reinterpret_cast<const float4*>(bias + f0);
  float r0 = fmaxf(dd * a0 + bv.x, 0.f);
  float r1 = fmaxf(dd * a1 + bv.y, 0.f);
  float r2 = fmaxf(dd * a2 + bv.z, 0.f);
  float r3 = fmaxf(dd * a3 + bv.w, 0.f);
  if (FUSE_T3) {
    float p0 = r0 * W3[(f0 + 0) * 2]     + r1 * W3[(f0 + 1) * 2]
             + r2 * W3[(f0 + 2) * 2]     + r3 * W3[(f0 + 3) * 2];
    float p1 = r0 * W3[(f0 + 0) * 2 + 1] + r1 * W3[(f0 + 1) * 2 + 1]
             + r2 * W3[(f0 + 2) * 2 + 1] + r3 * W3[(f0 + 3) * 2 + 1];
#pragma unroll
    for (int o = 32; o; o >>= 1) { p0 += __shfl_xor(p0, o); p1 += __shfl_xor(p1, o); }
    if (lane == 0) {
      t3[d * 2] = dd * p0;
      t3[d * 2 + 1] = dd * p1;
    }
  } else {
    ushort4 o;
    o.x = f2bf(r0); o.y = f2bf(r1); o.z = f2bf(r2); o.w = f2bf(r3);
    *reinterpret_cast<ushort4*>(h + ((size_t)d << 8) + f0) = o;
  }
}

// ------ fused layer-3 aggregation + mean pool: one block per graph --------
__global__ __launch_bounds__(448) void k_aggpool3(const float* __restrict__ t3,
                                                  const int* __restrict__ off,
                                                  const u16* __restrict__ csr,
                                                  const float* __restrict__ dis,
                                                  const float* __restrict__ b3,
                                                  float* __restrict__ out) {
  int g = blockIdx.x, t = threadIdx.x;
  int lane = t & 63, wv = t >> 6;
  float a0 = 0.f, a1 = 0.f;
  if (t < NODES_PER_GRAPH) {
    int d = g * NODES_PER_GRAPH + t;
    a0 = t3[d * 2]; a1 = t3[d * 2 + 1];
    int e = off[d], e1 = off[d + 1];
    while (e + 4 <= e1) {
      int s0 = csr[e], s1 = csr[e + 1], s2 = csr[e + 2], s3 = csr[e + 3];
      float2 v0 = *reinterpret_cast<const float2*>(t3 + s0 * 2);
      float2 v1 = *reinterpret_cast<const float2*>(t3 + s1 * 2);
      float2 v2 = *reinterpret_cast<const float2*>(t3 + s2 * 2);
      float2 v3 = *reinterpret_cast<const float2*>(t3 + s3 * 2);
      a0 += v0.x + v1.x + v2.x + v3.x;
      a1 += v0.y + v1.y + v2.y + v3.y;
      e += 4;
    }
    while (e < e1) {
      float2 v = *reinterpret_cast<const float2*>(t3 + csr[e] * 2);
      a0 += v.x; a1 += v.y; ++e;
    }
    float dd = dis[d];
    a0 *= dd; a1 *= dd;
  }
#pragma unroll
  for (int o = 32; o; o >>= 1) { a0 += __shfl_xor(a0, o); a1 += __shfl_xor(a1, o); }
  __shared__ float w0[8], w1[8];
  if (lane == 0) { w0[wv] = a0; w1[wv] = a1; }
  __syncthreads();
  if (t == 0) {
    float s0 = 0.f, s1 = 0.f;
#pragma unroll
    for (int i = 0; i < 7; ++i) { s0 += w0[i]; s1 += w1[i]; }
    out[g * 2]     = s0 * (1.0f / NODES_PER_GRAPH) + b3[0];
    out[g * 2 + 1] = s1 * (1.0f / NODES_PER_GRAPH) + b3[1];
  }
}

extern "C" void kernel_launch(void* const* d_in, const int* in_sizes, int n_in,
                              void* d_out, int out_size, void* d_ws, size_t ws_size,
                              hipStream_t stream) {
  const float* x  = (const float*)d_in[0];
  const int*   ei = (const int*)d_in[1];
  const float* W1 = (const float*)d_in[2];
  const float* b1 = (const float*)d_in[3];
  const float* W2 = (const float*)d_in[4];
  const float* b2 = (const float*)d_in[5];
  const float* W3 = (const float*)d_in[6];
  const float* b3 = (const float*)d_in[7];
  float* out = (float*)d_out;
  const int E = N_EDGES;
  const int* src = ei;
  const int* dst = ei + E;

  char* ws = (char*)d_ws;
  size_t o = 0;
  auto alloc = [&](size_t bytes) -> void* {
    void* p = ws + o;
    o += (bytes + 255) & ~(size_t)255;
    return p;
  };
  int8_t* tQ   = (int8_t*)alloc((size_t)N_NODES * H_DIM);
  float* rs4   = (float*)alloc((size_t)N_NODES * 4 * 4);
  u16* tB      = (u16*)alloc((size_t)N_NODES * H_DIM * 2);
  u16* W2T     = (u16*)alloc((size_t)H_DIM * H_DIM * 2);
  float* dis   = (float*)alloc((size_t)N_NODES * 4);
  int* counts  = (int*)alloc((size_t)N_NODES * 4);
  int* rank    = (int*)alloc((size_t)E * 4);
  int* csroff  = (int*)alloc((size_t)(N_NODES + 1) * 4);
  u16* csr     = (u16*)alloc((size_t)E * 2);
  float* t3    = (float*)alloc((size_t)N_NODES * 2 * 4);
  int* bsum    = (int*)alloc((size_t)NB_SCAN * 4);
  int* boff    = (int*)alloc((size_t)NB_SCAN * 4);
  int8_t* xq   = (int8_t*)alloc((size_t)N_NODES * K1Q);
  float* sx    = (float*)alloc((size_t)N_NODES * 4);
  int8_t* w1q  = (int8_t*)alloc((size_t)H_DIM * K1Q);
  float* sw1   = (float*)alloc((size_t)H_DIM * 4);

  k_zero<<<NB_SCAN, 256, 0, stream>>>(counts);
  // fuse1: histrank || quantx || prepw
  k_fuse1<<<HB + QB + H_DIM / 4 + H_DIM, 256, 0, stream>>>(
      dst, counts, rank, x, xq, sx, W1, W2, w1q, sw1, W2T);
  k_reduce<<<NB_SCAN, 256, 0, stream>>>(counts, bsum);
  k_scantop<<<1, 256, 0, stream>>>(bsum, boff, csroff + N_NODES);
  k_scanlocal<<<NB_SCAN, 256, 0, stream>>>(counts, boff, csroff, dis);
  // fuse2: layer-1 int8 GEMM || CSR placement
  k_fuse2<<<MB + HB, 256, 0, stream>>>(xq, sx, w1q, sw1, dis, tQ, rs4,
                                       src, dst, rank, csroff, csr);
  // layer 1 aggregation
  k_agg<false><<<N_NODES / 4, 256, 0, stream>>>(tQ, rs4, csroff, csr, dis, b1,
                                                tB, nullptr, nullptr, N_NODES);
  // layer 2 (bf16 MFMA; agg fused with layer-3 matmul -> t3)
  k_mmB<H_DIM><<<N_NODES / 64, 256, 0, stream>>>(tB, W2T, dis, tQ, rs4);
  k_agg<true><<<N_NODES / 4, 256, 0, stream>>>(tQ, rs4, csroff, csr, dis, b2,
                                               nullptr, W3, t3, N_NODES);
  // layer 3 aggregation fused with mean pool
  k_aggpool3<<<N_GRAPHS, 448, 0, stream>>>(t3, csroff, csr, dis, b3, out);
}

// Round 17
// 204.066 us; speedup vs baseline: 1.6952x; 1.0272x over previous
//
#include <hip/hip_runtime.h>
#include <hip/hip_bf16.h>
#include <stdint.h>

typedef __attribute__((ext_vector_type(8))) __bf16 bf16x8;
typedef __attribute__((ext_vector_type(4))) float f32x4;
typedef __attribute__((ext_vector_type(4))) int i32x4;
typedef unsigned short u16;

#define N_NODES 51200
#define N_EDGES 819200
#define F_IN 400
#define K1Q 448
#define H_DIM 256
#define C_OUT 2
#define N_GRAPHS 128
#define NODES_PER_GRAPH 400
#define NB_SCAN (N_NODES / 256)   // 200 blocks
#define HB 3200                   // histrank block-slots in fuse1
#define QB 12800                  // quantx block-slots in fuse1
#define MB 800                    // mm8 block-slots in fuse2

__device__ __forceinline__ u16 f2bf(float f) {
  uint32_t u = __builtin_bit_cast(uint32_t, f);
  u = (u + 0x7fffu + ((u >> 16) & 1u)) >> 16;
  return (u16)u;
}

typedef const __attribute__((address_space(1))) unsigned int* gas_ptr;
typedef __attribute__((address_space(3))) unsigned int* las_ptr;
__device__ __forceinline__ void gl_lds16(const void* g, void* l) {
  __builtin_amdgcn_global_load_lds((gas_ptr)g, (las_ptr)l, 16, 0, 0);
}
__device__ __forceinline__ void wait_vm0()   { asm volatile("s_waitcnt vmcnt(0)" ::: "memory"); }
__device__ __forceinline__ void wait_vm5()   { asm volatile("s_waitcnt vmcnt(5)" ::: "memory"); }
__device__ __forceinline__ void wait_lgkm0() { asm volatile("s_waitcnt lgkmcnt(0)" ::: "memory"); }

// ------ multi-block zero (rocclr small-buffer fill path is serial) --------
__global__ void k_zero(int* __restrict__ p) {
  p[blockIdx.x * 256 + threadIdx.x] = 0;
}

// ===== FUSE 1 (1:4 interleaved): bid%5==0 -> histrank; else quantx/prepw ==
// Interleaving keeps atomic-waiting blocks and HBM-streaming blocks
// co-resident from t=0 (head-of-queue serialization fix, r16 post-mortem).
__global__ __launch_bounds__(256) void k_fuse1(
    const int* __restrict__ dst, int* __restrict__ counts, int* __restrict__ rank,
    const float* __restrict__ x, int8_t* __restrict__ xq, float* __restrict__ sx,
    const float* __restrict__ W1, const float* __restrict__ W2,
    int8_t* __restrict__ w1q, float* __restrict__ sw1, u16* __restrict__ W2T) {
  int bid = blockIdx.x;
  int wid = threadIdx.x >> 6, lane = threadIdx.x & 63;
  if (bid % 5 == 0) {
    // ---- histogram + rank handout
    int hb = bid / 5;
    if (hb >= HB) return;               // 80 spare slots
    int e = hb * 256 + threadIdx.x;
    rank[e] = atomicAdd(&counts[dst[e]], 1);
    return;
  }
  int oid = bid - bid / 5 - 1;          // dense index over non-multiples of 5
  if (oid < QB) {
    // ---- x -> per-row int8
    int d = oid * 4 + wid;
    float4 v0 = {0.f, 0.f, 0.f, 0.f}, v1 = {0.f, 0.f, 0.f, 0.f};
    if (lane < 50) {
      const float* p = x + (size_t)d * F_IN + lane * 8;
      v0 = *reinterpret_cast<const float4*>(p);
      v1 = *reinterpret_cast<const float4*>(p + 4);
    }
    float m = fmaxf(fmaxf(fmaxf(fabsf(v0.x), fabsf(v0.y)), fmaxf(fabsf(v0.z), fabsf(v0.w))),
                    fmaxf(fmaxf(fabsf(v1.x), fabsf(v1.y)), fmaxf(fabsf(v1.z), fabsf(v1.w))));
#pragma unroll
    for (int o = 32; o; o >>= 1) m = fmaxf(m, __shfl_xor(m, o));
    float inv = (m > 0.f) ? 127.0f / m : 0.f;
    if (lane < 56) {
      uint32_t lo = 0, hi = 0;
      if (lane < 50) {
        int q0 = (int)rintf(v0.x * inv), q1 = (int)rintf(v0.y * inv);
        int q2 = (int)rintf(v0.z * inv), q3 = (int)rintf(v0.w * inv);
        int q4 = (int)rintf(v1.x * inv), q5 = (int)rintf(v1.y * inv);
        int q6 = (int)rintf(v1.z * inv), q7 = (int)rintf(v1.w * inv);
        lo = (uint32_t)(q0 & 255) | ((uint32_t)(q1 & 255) << 8) |
             ((uint32_t)(q2 & 255) << 16) | ((uint32_t)(q3 & 255) << 24);
        hi = (uint32_t)(q4 & 255) | ((uint32_t)(q5 & 255) << 8) |
             ((uint32_t)(q6 & 255) << 16) | ((uint32_t)(q7 & 255) << 24);
      }
      uint2 o8; o8.x = lo; o8.y = hi;
      *reinterpret_cast<uint2*>(xq + (size_t)d * K1Q + lane * 8) = o8;
    }
    if (lane == 0) sx[d] = m * (1.0f / 127.0f);
  } else {
    // ---- weight prep
    int b = oid - QB;                   // [0, 320)
    if (b < H_DIM / 4) {
      int n = b * 4 + wid;
      float vals[7];
      float m = 0.f;
#pragma unroll
      for (int j = 0; j < 7; ++j) {
        int k = lane + j * 64;
        vals[j] = (k < F_IN) ? W1[(size_t)k * H_DIM + n] : 0.f;
        m = fmaxf(m, fabsf(vals[j]));
      }
#pragma unroll
      for (int o = 32; o; o >>= 1) m = fmaxf(m, __shfl_xor(m, o));
      float inv = (m > 0.f) ? 127.0f / m : 0.f;
#pragma unroll
      for (int j = 0; j < 7; ++j) {
        int k = lane + j * 64;
        w1q[(size_t)n * K1Q + k] = (int8_t)(int)rintf(vals[j] * inv);
      }
      if (lane == 0) sw1[n] = m * (1.0f / 127.0f);
    } else {
      int k = b - H_DIM / 4, n = threadIdx.x;
      W2T[n * H_DIM + k] = f2bf(W2[k * H_DIM + n]);
    }
  }
}

// ---------------- hierarchical scan: phase 1, per-block sums --------------
__global__ __launch_bounds__(256) void k_reduce(const int* __restrict__ counts,
                                                int* __restrict__ bsum) {
  int i = blockIdx.x * 256 + threadIdx.x;
  int v = counts[i];
#pragma unroll
  for (int o = 32; o; o >>= 1) v += __shfl_xor(v, o);
  __shared__ int wsum[4];
  if ((threadIdx.x & 63) == 0) wsum[threadIdx.x >> 6] = v;
  __syncthreads();
  if (threadIdx.x == 0) bsum[blockIdx.x] = wsum[0] + wsum[1] + wsum[2] + wsum[3];
}

// ---------------- phase 2: scan the 200 block sums (one small block) ------
__global__ __launch_bounds__(256) void k_scantop(const int* __restrict__ bsum,
                                                 int* __restrict__ boff,
                                                 int* __restrict__ off_last) {
  __shared__ int s[256];
  int t = threadIdx.x;
  int v = (t < NB_SCAN) ? bsum[t] : 0;
  s[t] = v;
  __syncthreads();
  for (int d = 1; d < 256; d <<= 1) {
    int u = (t >= d) ? s[t - d] : 0;
    __syncthreads();
    s[t] += u;
    __syncthreads();
  }
  if (t < NB_SCAN) boff[t] = s[t] - v;   // exclusive prefix of block sums
  if (t == 0) *off_last = N_EDGES;       // off[N] = total edges
}

// ---------------- phase 3: local scan + block offset; also dis ------------
__global__ __launch_bounds__(256) void k_scanlocal(const int* __restrict__ counts,
                                                   const int* __restrict__ boff,
                                                   int* __restrict__ off,
                                                   float* __restrict__ dis) {
  __shared__ int s[256];
  int t = threadIdx.x;
  int i = blockIdx.x * 256 + t;
  int v = counts[i];
  s[t] = v;
  __syncthreads();
  for (int d = 1; d < 256; d <<= 1) {
    int u = (t >= d) ? s[t - d] : 0;
    __syncthreads();
    s[t] += u;
    __syncthreads();
  }
  int ex = boff[blockIdx.x] + s[t] - v;
  off[i] = ex;
  dis[i] = rsqrtf(1.0f + (float)v);
}

// ===== FUSE 2 (1:4 interleaved): bid%5==0 -> mm8 tile; else place =========
__global__ __launch_bounds__(256) void k_fuse2(
    const int8_t* __restrict__ Aq, const float* __restrict__ srow,
    const int8_t* __restrict__ Bq, const float* __restrict__ scol,
    const float* __restrict__ dis, int8_t* __restrict__ Cq, float* __restrict__ rs4,
    const int* __restrict__ src, const int* __restrict__ dst,
    const int* __restrict__ rank, const int* __restrict__ off,
    u16* __restrict__ csr_src) {
  constexpr int KB = K1Q, NS = KB >> 6;   // 7
  __shared__ __align__(16) int8_t As[2][64 * 64];
  __shared__ __align__(16) int8_t Bs[2][256 * 64];
  const int bid = blockIdx.x;
  if (bid % 5 != 0) {
    // ---- atomic-free placement (u16)
    int oid = bid - bid / 5 - 1;        // [0, 3200)
    int e = oid * 256 + threadIdx.x;
    int d = dst[e];
    csr_src[off[d] + rank[e]] = (u16)src[e];
    return;
  }
  const int tid = threadIdx.x;
  const int lane = tid & 63, wid = tid >> 6;
  const int lr = lane & 15, lg = lane >> 4;
  const int m0 = (bid / 5) * 64;
  const int aRow = tid >> 2;
  const int aSl = ((tid & 3) ^ ((tid >> 3) & 3)) << 4;
  const int bRow16 = lane >> 2;
  const int bSl = ((lane & 3) ^ ((lane >> 3) & 3)) << 4;
  const int rSl = (lg ^ ((lr >> 1) & 3)) << 4;

  auto stage = [&](int s, int b) {
    int k0 = s << 6;
    gl_lds16(Aq + (size_t)(m0 + aRow) * KB + k0 + aSl, (char*)As[b] + wid * 1024);
#pragma unroll
    for (int j = 0; j < 4; ++j) {
      int c = wid * 4 + j;
      gl_lds16(Bq + (size_t)(c * 16 + bRow16) * KB + k0 + bSl, (char*)Bs[b] + c * 1024);
    }
  };

  stage(0, 0);
  stage(1, 1);

  i32x4 acc[4][4] = {};
  for (int k = 0; k < NS; ++k) {
    const int b = k & 1;
    if (k + 1 < NS) wait_vm5(); else wait_vm0();
    __builtin_amdgcn_sched_barrier(0);
    __builtin_amdgcn_s_barrier();
    __builtin_amdgcn_sched_barrier(0);
    i32x4 af[4], bfr[4];
#pragma unroll
    for (int m = 0; m < 4; ++m)
      af[m] = *reinterpret_cast<const i32x4*>(&As[b][(m * 16 + lr) * 64 + rSl]);
#pragma unroll
    for (int n = 0; n < 4; ++n)
      bfr[n] = *reinterpret_cast<const i32x4*>(&Bs[b][(wid * 64 + n * 16 + lr) * 64 + rSl]);
    __builtin_amdgcn_sched_barrier(0);
    wait_lgkm0();
    __builtin_amdgcn_sched_barrier(0);
    __builtin_amdgcn_s_barrier();
    __builtin_amdgcn_sched_barrier(0);
    if (k + 2 < NS) stage(k + 2, b);
    __builtin_amdgcn_sched_barrier(0);
#pragma unroll
    for (int m = 0; m < 4; ++m)
#pragma unroll
      for (int n = 0; n < 4; ++n)
        acc[m][n] = __builtin_amdgcn_mfma_i32_16x16x64_i8(af[m], bfr[n], acc[m][n], 0, 0, 0);
  }

  // ---- epilogue: dequant (scol; srow cancels in requant) + int8 requant
  float scv[4];
#pragma unroll
  for (int n = 0; n < 4; ++n) scv[n] = scol[wid * 64 + n * 16 + lr];
  float pam[4][4];
#pragma unroll
  for (int m = 0; m < 4; ++m)
#pragma unroll
    for (int r = 0; r < 4; ++r) {
      float v0 = fabsf((float)acc[m][0][r] * scv[0]);
      float v1 = fabsf((float)acc[m][1][r] * scv[1]);
      float v2 = fabsf((float)acc[m][2][r] * scv[2]);
      float v3 = fabsf((float)acc[m][3][r] * scv[3]);
      pam[m][r] = fmaxf(fmaxf(v0, v1), fmaxf(v2, v3));
    }
#pragma unroll
  for (int o = 1; o < 16; o <<= 1)
#pragma unroll
    for (int m = 0; m < 4; ++m)
#pragma unroll
      for (int r = 0; r < 4; ++r)
        pam[m][r] = fmaxf(pam[m][r], __shfl_xor(pam[m][r], o));
#pragma unroll
  for (int m = 0; m < 4; ++m)
#pragma unroll
    for (int r = 0; r < 4; ++r) {
      int grow = m0 + m * 16 + lg * 4 + r;
      float fm = fmaxf(pam[m][r], 1e-20f);
      float inv = 127.0f / fm;
      if (lr == 0) rs4[(size_t)grow * 4 + wid] = dis[grow] * srow[grow] * fm * (1.0f / 127.0f);
#pragma unroll
      for (int n = 0; n < 4; ++n) {
        int q = (int)rintf((float)acc[m][n][r] * scv[n] * inv);
        Cq[(size_t)grow * H_DIM + wid * 64 + n * 16 + lr] = (int8_t)q;
      }
    }
}

// ------- layer-2 bf16 MFMA GEMM: 2-deep counted-vmcnt pipe ----------------
template <int KB>
__global__ __launch_bounds__(256) void k_mmB(const u16* __restrict__ A,
                                             const u16* __restrict__ BT,
                                             const float* __restrict__ dis,
                                             int8_t* __restrict__ Cq,
                                             float* __restrict__ rs4) {
  constexpr int NS = KB >> 5;
  __shared__ __align__(16) u16 As[2][64 * 32];
  __shared__ __align__(16) u16 Bs[2][256 * 32];
  const int tid = threadIdx.x;
  const int lane = tid & 63, wid = tid >> 6;
  const int lr = lane & 15, lg = lane >> 4;
  const int m0 = blockIdx.x * 64;
  const int sseg = (((lane & 3) ^ ((lane >> 3) & 3)) << 3);
  const int arow = tid >> 2;
  const int brow = lane >> 2;
  const int rs8 = ((lg ^ ((lr >> 1) & 3)) << 3);

  auto stage = [&](int s, int b) {
    int k0 = s << 5;
    gl_lds16(A + (size_t)(m0 + arow) * KB + k0 + sseg, (char*)As[b] + wid * 1024);
#pragma unroll
    for (int j = 0; j < 4; ++j) {
      int c = wid * 4 + j;
      gl_lds16(BT + (size_t)(c * 16 + brow) * KB + k0 + sseg, (char*)Bs[b] + c * 1024);
    }
  };

  stage(0, 0);
  stage(1, 1);

  f32x4 acc[4][4] = {};
  for (int k = 0; k < NS; ++k) {
    const int b = k & 1;
    if (k + 1 < NS) wait_vm5(); else wait_vm0();
    __builtin_amdgcn_sched_barrier(0);
    __builtin_amdgcn_s_barrier();
    __builtin_amdgcn_sched_barrier(0);
    bf16x8 af[4], bfr[4];
#pragma unroll
    for (int m = 0; m < 4; ++m)
      af[m] = *reinterpret_cast<const bf16x8*>(&As[b][(m * 16 + lr) * 32 + rs8]);
#pragma unroll
    for (int n = 0; n < 4; ++n)
      bfr[n] = *reinterpret_cast<const bf16x8*>(&Bs[b][(wid * 64 + n * 16 + lr) * 32 + rs8]);
    __builtin_amdgcn_sched_barrier(0);
    wait_lgkm0();
    __builtin_amdgcn_sched_barrier(0);
    __builtin_amdgcn_s_barrier();
    __builtin_amdgcn_sched_barrier(0);
    if (k + 2 < NS) stage(k + 2, b);
    __builtin_amdgcn_sched_barrier(0);
#pragma unroll
    for (int m = 0; m < 4; ++m)
#pragma unroll
      for (int n = 0; n < 4; ++n)
        acc[m][n] = __builtin_amdgcn_mfma_f32_16x16x32_bf16(af[m], bfr[n], acc[m][n], 0, 0, 0);
  }

  // ---- epilogue: per-quadrant int8 quantization
  float pam[4][4];
#pragma unroll
  for (int m = 0; m < 4; ++m)
#pragma unroll
    for (int r = 0; r < 4; ++r) {
      float v0 = fabsf(acc[m][0][r]), v1 = fabsf(acc[m][1][r]);
      float v2 = fabsf(acc[m][2][r]), v3 = fabsf(acc[m][3][r]);
      pam[m][r] = fmaxf(fmaxf(v0, v1), fmaxf(v2, v3));
    }
#pragma unroll
  for (int o = 1; o < 16; o <<= 1)
#pragma unroll
    for (int m = 0; m < 4; ++m)
#pragma unroll
      for (int r = 0; r < 4; ++r)
        pam[m][r] = fmaxf(pam[m][r], __shfl_xor(pam[m][r], o));
#pragma unroll
  for (int m = 0; m < 4; ++m)
#pragma unroll
    for (int r = 0; r < 4; ++r) {
      int grow = m0 + m * 16 + lg * 4 + r;
      float fm = fmaxf(pam[m][r], 1e-20f);
      float inv = 127.0f / fm;
      if (lr == 0) rs4[(size_t)grow * 4 + wid] = dis[grow] * fm * (1.0f / 127.0f);
#pragma unroll
      for (int n = 0; n < 4; ++n) {
        int q = (int)rintf(acc[m][n][r] * inv);
        Cq[(size_t)grow * H_DIM + wid * 64 + n * 16 + lr] = (int8_t)q;
      }
    }
}

// ------- int8 gather group: U independent row loads + quadrant scales -----
template <int U>
__device__ __forceinline__ void gath8(const int8_t* __restrict__ tq,
                                      const float* __restrict__ rs4,
                                      const u16* __restrict__ csr, int e,
                                      int f0, int qo,
                                      float& a0, float& a1, float& a2, float& a3) {
  int s[U];
  uint32_t v[U];
  float sc[U];
#pragma unroll
  for (int i = 0; i < U; ++i) s[i] = csr[e + i];
#pragma unroll
  for (int i = 0; i < U; ++i) {
    v[i] = *reinterpret_cast<const uint32_t*>(tq + ((size_t)s[i] << 8) + f0);
    sc[i] = rs4[((size_t)s[i] << 2) + qo];
  }
#pragma unroll
  for (int i = 0; i < U; ++i) {
    a0 += sc[i] * (float)(int8_t)(v[i]);
    a1 += sc[i] * (float)(int8_t)(v[i] >> 8);
    a2 += sc[i] * (float)(int8_t)(v[i] >> 16);
    a3 += sc[i] * (float)(int8_t)(v[i] >> 24);
  }
}

// ------- aggregation on quantized pre-scaled rows ------------------------
template <bool FUSE_T3>
__global__ __launch_bounds__(256) void k_agg(const int8_t* __restrict__ tq,
                                             const float* __restrict__ rs4,
                                             const int* __restrict__ off,
                                             const u16* __restrict__ csr,
                                             const float* __restrict__ dis,
                                             const float* __restrict__ bias,
                                             u16* __restrict__ h,
                                             const float* __restrict__ W3,
                                             float* __restrict__ t3, int N) {
  int wid = threadIdx.x >> 6, lane = threadIdx.x & 63;
  int d = blockIdx.x * 4 + wid;
  if (d >= N) return;
  int f0 = lane * 4;
  int qo = lane >> 4;
  float a0, a1, a2, a3;
  {
    uint32_t v = *reinterpret_cast<const uint32_t*>(tq + ((size_t)d << 8) + f0);
    float sc = rs4[((size_t)d << 2) + qo];
    a0 = sc * (float)(int8_t)(v);
    a1 = sc * (float)(int8_t)(v >> 8);
    a2 = sc * (float)(int8_t)(v >> 16);
    a3 = sc * (float)(int8_t)(v >> 24);
  }
  int e = off[d], e1 = off[d + 1];
  while (e + 8 <= e1) { gath8<8>(tq, rs4, csr, e, f0, qo, a0, a1, a2, a3); e += 8; }
  if (e + 4 <= e1) { gath8<4>(tq, rs4, csr, e, f0, qo, a0, a1, a2, a3); e += 4; }
  if (e + 2 <= e1) { gath8<2>(tq, rs4, csr, e, f0, qo, a0, a1, a2, a3); e += 2; }
  if (e < e1)      { gath8<1>(tq, rs4, csr, e, f0, qo, a0, a1, a2, a3); }
  float dd = dis[d];
  float4 bv = *reinterpret_cast<const float4*>(bias + f0);
  float r0 = fmaxf(dd * a0 + bv.x, 0.f);
  float r1 = fmaxf(dd * a1 + bv.y, 0.f);
  float r2 = fmaxf(dd * a2 + bv.z, 0.f);
  float r3 = fmaxf(dd * a3 + bv.w, 0.f);
  if (FUSE_T3) {
    float p0 = r0 * W3[(f0 + 0) * 2]     + r1 * W3[(f0 + 1) * 2]
             + r2 * W3[(f0 + 2) * 2]     + r3 * W3[(f0 + 3) * 2];
    float p1 = r0 * W3[(f0 + 0) * 2 + 1] + r1 * W3[(f0 + 1) * 2 + 1]
             + r2 * W3[(f0 + 2) * 2 + 1] + r3 * W3[(f0 + 3) * 2 + 1];
#pragma unroll
    for (int o = 32; o; o >>= 1) { p0 += __shfl_xor(p0, o); p1 += __shfl_xor(p1, o); }
    if (lane == 0) {
      t3[d * 2] = dd * p0;
      t3[d * 2 + 1] = dd * p1;
    }
  } else {
    ushort4 o;
    o.x = f2bf(r0); o.y = f2bf(r1); o.z = f2bf(r2); o.w = f2bf(r3);
    *reinterpret_cast<ushort4*>(h + ((size_t)d << 8) + f0) = o;
  }
}

// ------ fused layer-3 aggregation + mean pool: one block per graph --------
__global__ __launch_bounds__(448) void k_aggpool3(const float* __restrict__ t3,
                                                  const int* __restrict__ off,
                                                  const u16* __restrict__ csr,
                                                  const float* __restrict__ dis,
                                                  const float* __restrict__ b3,
                                                  float* __restrict__ out) {
  int g = blockIdx.x, t = threadIdx.x;
  int lane = t & 63, wv = t >> 6;
  float a0 = 0.f, a1 = 0.f;
  if (t < NODES_PER_GRAPH) {
    int d = g * NODES_PER_GRAPH + t;
    a0 = t3[d * 2]; a1 = t3[d * 2 + 1];
    int e = off[d], e1 = off[d + 1];
    while (e + 4 <= e1) {
      int s0 = csr[e], s1 = csr[e + 1], s2 = csr[e + 2], s3 = csr[e + 3];
      float2 v0 = *reinterpret_cast<const float2*>(t3 + s0 * 2);
      float2 v1 = *reinterpret_cast<const float2*>(t3 + s1 * 2);
      float2 v2 = *reinterpret_cast<const float2*>(t3 + s2 * 2);
      float2 v3 = *reinterpret_cast<const float2*>(t3 + s3 * 2);
      a0 += v0.x + v1.x + v2.x + v3.x;
      a1 += v0.y + v1.y + v2.y + v3.y;
      e += 4;
    }
    while (e < e1) {
      float2 v = *reinterpret_cast<const float2*>(t3 + csr[e] * 2);
      a0 += v.x; a1 += v.y; ++e;
    }
    float dd = dis[d];
    a0 *= dd; a1 *= dd;
  }
#pragma unroll
  for (int o = 32; o; o >>= 1) { a0 += __shfl_xor(a0, o); a1 += __shfl_xor(a1, o); }
  __shared__ float w0[8], w1[8];
  if (lane == 0) { w0[wv] = a0; w1[wv] = a1; }
  __syncthreads();
  if (t == 0) {
    float s0 = 0.f, s1 = 0.f;
#pragma unroll
    for (int i = 0; i < 7; ++i) { s0 += w0[i]; s1 += w1[i]; }
    out[g * 2]     = s0 * (1.0f / NODES_PER_GRAPH) + b3[0];
    out[g * 2 + 1] = s1 * (1.0f / NODES_PER_GRAPH) + b3[1];
  }
}

extern "C" void kernel_launch(void* const* d_in, const int* in_sizes, int n_in,
                              void* d_out, int out_size, void* d_ws, size_t ws_size,
                              hipStream_t stream) {
  const float* x  = (const float*)d_in[0];
  const int*   ei = (const int*)d_in[1];
  const float* W1 = (const float*)d_in[2];
  const float* b1 = (const float*)d_in[3];
  const float* W2 = (const float*)d_in[4];
  const float* b2 = (const float*)d_in[5];
  const float* W3 = (const float*)d_in[6];
  const float* b3 = (const float*)d_in[7];
  float* out = (float*)d_out;
  const int E = N_EDGES;
  const int* src = ei;
  const int* dst = ei + E;

  char* ws = (char*)d_ws;
  size_t o = 0;
  auto alloc = [&](size_t bytes) -> void* {
    void* p = ws + o;
    o += (bytes + 255) & ~(size_t)255;
    return p;
  };
  int8_t* tQ   = (int8_t*)alloc((size_t)N_NODES * H_DIM);
  float* rs4   = (float*)alloc((size_t)N_NODES * 4 * 4);
  u16* tB      = (u16*)alloc((size_t)N_NODES * H_DIM * 2);
  u16* W2T     = (u16*)alloc((size_t)H_DIM * H_DIM * 2);
  float* dis   = (float*)alloc((size_t)N_NODES * 4);
  int* counts  = (int*)alloc((size_t)N_NODES * 4);
  int* rank    = (int*)alloc((size_t)E * 4);
  int* csroff  = (int*)alloc((size_t)(N_NODES + 1) * 4);
  u16* csr     = (u16*)alloc((size_t)E * 2);
  float* t3    = (float*)alloc((size_t)N_NODES * 2 * 4);
  int* bsum    = (int*)alloc((size_t)NB_SCAN * 4);
  int* boff    = (int*)alloc((size_t)NB_SCAN * 4);
  int8_t* xq   = (int8_t*)alloc((size_t)N_NODES * K1Q);
  float* sx    = (float*)alloc((size_t)N_NODES * 4);
  int8_t* w1q  = (int8_t*)alloc((size_t)H_DIM * K1Q);
  float* sw1   = (float*)alloc((size_t)H_DIM * 4);

  k_zero<<<NB_SCAN, 256, 0, stream>>>(counts);
  // fuse1 (interleaved 1:4): histrank || quantx || prepw
  // grid 16400: 3280 h-slots (3200 used) + 13120 others (12800 quantx + 320 prepw)
  k_fuse1<<<16400, 256, 0, stream>>>(
      dst, counts, rank, x, xq, sx, W1, W2, w1q, sw1, W2T);
  k_reduce<<<NB_SCAN, 256, 0, stream>>>(counts, bsum);
  k_scantop<<<1, 256, 0, stream>>>(bsum, boff, csroff + N_NODES);
  k_scanlocal<<<NB_SCAN, 256, 0, stream>>>(counts, boff, csroff, dis);
  // fuse2 (interleaved 1:4): layer-1 int8 GEMM || CSR placement
  k_fuse2<<<MB + HB, 256, 0, stream>>>(xq, sx, w1q, sw1, dis, tQ, rs4,
                                       src, dst, rank, csroff, csr);
  // layer 1 aggregation
  k_agg<false><<<N_NODES / 4, 256, 0, stream>>>(tQ, rs4, csroff, csr, dis, b1,
                                                tB, nullptr, nullptr, N_NODES);
  // layer 2 (bf16 MFMA; agg fused with layer-3 matmul -> t3)
  k_mmB<H_DIM><<<N_NODES / 64, 256, 0, stream>>>(tB, W2T, dis, tQ, rs4);
  k_agg<true><<<N_NODES / 4, 256, 0, stream>>>(tQ, rs4, csroff, csr, dis, b2,
                                               nullptr, W3, t3, N_NODES);
  // layer 3 aggregation fused with mean pool
  k_aggpool3<<<N_GRAPHS, 448, 0, stream>>>(t3, csroff, csr, dis, b3, out);
}